// Round 10
// baseline (934.164 us; speedup 1.0000x reference)
//
#include <hip/hip_runtime.h>
#include <hip/hip_bf16.h>

typedef __hip_bfloat16 bf16_t;

#define N_NODES 10000
#define N_EDGES 100000
#define N_BONDS 1000
#define RPW 2

__device__ __forceinline__ float bf2f(bf16_t v){ return __bfloat162float(v); }
__device__ __forceinline__ bf16_t f2bf(float v){ return __float2bfloat16(v); }
__device__ __forceinline__ int iabs(int x){ return x<0?-x:x; }

// Compile-time CG nonzero superset mask
constexpr bool cg_nz(int l1,int l2,int l3,int i,int j,int k){
  int m1=i-l1, m2=j-l2, m3=k-l3;
  int neg=(m1<0)+(m2<0)+(m3<0);
  if (((neg ^ (l1+l2+l3)) & 1)!=0) return false;
  int a1=m1<0?-m1:m1, a2=m2<0?-m2:m2, a3=m3<0?-m3:m3;
  return (a3==a1+a2)||(a3==a1-a2)||(a3==a2-a1);
}

__device__ __forceinline__ void stout(void* out, size_t idx, float v, bool f32o){
  if (f32o) ((float*)out)[idx]=v;
  else      ((bf16_t*)out)[idx]=f2bf(v);
}

struct CvtArgs {
  const void* src[19];
  float* dst[19];
  int n[19];
};

// =====================================================================
// Convert with inline dtype detection (nnb==10.0; bf16 -> u16[0]==0x4120)
// Block 0 thread 0 persists the flag for the output kernels.
// =====================================================================
__global__ __launch_bounds__(256) void convert_k(CvtArgs a,
    const unsigned short* __restrict__ nnb_raw, int* flag){
  bool f32 = (nnb_raw[0]!=0x4120);
  if (blockIdx.x==0 && threadIdx.x==0) *flag = f32?1:0;
  int tid = blockIdx.x*256+threadIdx.x;
  int nth = gridDim.x*256;
  for(int t=0;t<19;++t){
    int n=a.n[t];
    float* d=a.dst[t];
    if (f32){
      const float* s=(const float*)a.src[t];
      for(int i=tid;i<n;i+=nth) d[i]=s[i];
    } else {
      const bf16_t* s=(const bf16_t*)a.src[t];
      for(int i=tid;i<n;i+=nth) d[i]=bf2f(s[i]);
    }
  }
}

// =====================================================================
// CSR build
// =====================================================================
__global__ __launch_bounds__(256) void csr_count_k(const int* __restrict__ edst, int* __restrict__ cnt){
  int e=blockIdx.x*256+threadIdx.x; if(e>=N_EDGES) return;
  atomicAdd(&cnt[edst[e]],1);
}

__global__ __launch_bounds__(256) void csr_scan_k(const int* __restrict__ cnt,
    int* __restrict__ rowptr, int* __restrict__ pos){
  __shared__ int ssum[256];
  int t=threadIdx.x;
  int base=t*40;
  int s=0;
  for(int i=0;i<40;++i){ int idx=base+i; s += (idx<N_NODES)? cnt[idx]:0; }
  ssum[t]=s; __syncthreads();
  if(t==0){ int run=0; for(int i=0;i<256;++i){ int v=ssum[i]; ssum[i]=run; run+=v; } }
  __syncthreads();
  int run=ssum[t];
  for(int i=0;i<40;++i){
    int idx=base+i;
    if(idx<N_NODES){ rowptr[idx]=run; pos[idx]=run; run+=cnt[idx]; }
  }
  if(t==255) rowptr[N_NODES]=run;
}

__global__ __launch_bounds__(256) void csr_scatter_k(const int* __restrict__ edst,
    int* __restrict__ pos, int* __restrict__ sorted){
  int e=blockIdx.x*256+threadIdx.x; if(e>=N_EDGES) return;
  int p=atomicAdd(&pos[edst[e]],1);
  sorted[p]=e;
}

// =====================================================================
// CG tables
// =====================================================================
__device__ __forceinline__ double dfact(int n){
  const double F[11]={1.,1.,2.,6.,24.,120.,720.,5040.,40320.,362880.,3628800.};
  return F[n];
}

__device__ double cgc_d(int j1,int m1,int j2,int m2,int j3,int m3){
  if (m1+m2!=m3) return 0.0;
  double pre = sqrt((double)(2*j3+1)*dfact(j3+j1-j2)*dfact(j3-j1+j2)*dfact(j1+j2-j3)/dfact(j1+j2+j3+1));
  pre *= sqrt(dfact(j3+m3)*dfact(j3-m3)*dfact(j1-m1)*dfact(j1+m1)*dfact(j2-m2)*dfact(j2+m2));
  int k0 = max(0, max(j2-j3-m1, j1-j3+m2));
  int k1 = min(j1+j2-j3, min(j1-m1, j2+m2));
  double s=0.0;
  for(int k=k0;k<=k1;++k)
    s += ((k&1)?-1.0:1.0)/(dfact(k)*dfact(j1+j2-j3-k)*dfact(j1-m1-k)*dfact(j2+m2-k)*dfact(j3-j2+m1+k)*dfact(j3-j1-m2+k));
  return pre*s;
}

__device__ void c2r_d(int l,int a,int m,double&re,double&im){
  re=0.0; im=0.0;
  const double r2 = 0.7071067811865475244;
  int mu = a-l;
  if (mu==0){ if (m==l) re=1.0; return; }
  if (mu>0){
    if (m==l+mu) re = (mu&1)? -r2 : r2;
    else if (m==l-mu) re = r2;
  } else {
    int nu=-mu;
    if (m==l-nu) im = r2;
    else if (m==l+nu) im = (nu&1)? r2 : -r2;
  }
}

__global__ __launch_bounds__(128) void cg_init_k(float* cg){
  int b=blockIdx.x;
  int l1=b/9, l2=(b/3)%3, l3=b%3;
  if (l3 < iabs(l1-l2) || l3 > l1+l2) return;
  int n1=2*l1+1,n2=2*l2+1,n3=2*l3+1,n=n1*n2*n3;
  __shared__ double sRe[125], sIm[125];
  __shared__ int sPick;
  int t=threadIdx.x;
  if (t<n){
    int a=t/(n2*n3), bb=(t/n3)%n2, c=t%n3;
    double re=0.0, im=0.0;
    for(int m1=0;m1<n1;++m1){
      double q1r,q1i; c2r_d(l1,a,m1,q1r,q1i);
      if (q1r==0.0 && q1i==0.0) continue;
      for(int m2=0;m2<n2;++m2){
        double q2r,q2i; c2r_d(l2,bb,m2,q2r,q2i);
        if (q2r==0.0 && q2i==0.0) continue;
        int m3=(m1-l1)+(m2-l2)+l3;
        if (m3<0||m3>=n3) continue;
        double q3r,q3i; c2r_d(l3,c,m3,q3r,q3i); q3i=-q3i;
        double C = cgc_d(l1,m1-l1,l2,m2-l2,l3,m3-l3);
        if (C==0.0) continue;
        double ar = q1r*q2r - q1i*q2i;
        double ai = q1r*q2i + q1i*q2r;
        re += (ar*q3r - ai*q3i)*C;
        im += (ar*q3i + ai*q3r)*C;
      }
    }
    sRe[t]=re; sIm[t]=im;
  }
  __syncthreads();
  if (t==0){
    double s1=0.0,s2=0.0;
    for(int i=0;i<n;++i){ s1+=fabs(sRe[i]); s2+=fabs(sIm[i]); }
    sPick = (s1>=s2)?1:0;
  }
  __syncthreads();
  if (t<n) cg[b*125+t] = (float)(sPick? sRe[t] : sIm[t]);
}

// =====================================================================
// Stage A
// =====================================================================
__global__ __launch_bounds__(256) void nodeA_k(const float* __restrict__ fin,
                                               const float* __restrict__ w,
                                               float* __restrict__ x1){
  int n=blockIdx.x*256+threadIdx.x; if(n>=N_NODES) return;
  float f0=fin[2*n], f1=fin[2*n+1];
  const float r2=0.70710678f;
  x1[2*n]   = tanhf((f0*w[0]+f1*w[2])*r2);
  x1[2*n+1] = tanhf((f0*w[1]+f1*w[3])*r2);
}

// MLP [1,16,16,16]
__device__ __forceinline__ void mlp16(float e, const float* w, float* h){
  float a[16];
  #pragma unroll
  for(int j=0;j<16;++j) a[j]=fmaxf(e*w[j],0.f);
  float b[16];
  #pragma unroll
  for(int j=0;j<16;++j){
    float s=0.f;
    #pragma unroll
    for(int i=0;i<16;++i) s+=a[i]*w[16+i*16+j];
    b[j]=fmaxf(s*0.25f,0.f);
  }
  #pragma unroll
  for(int j=0;j<16;++j){
    float s=0.f;
    #pragma unroll
    for(int i=0;i<16;++i) s+=b[i]*w[272+i*16+j];
    h[j]=fmaxf(s*0.25f,0.f);
  }
}

// =====================================================================
// Fused h-MLPs: blocks [0,391) -> h1, [391,782) -> h2, [782,794) -> hb
// =====================================================================
__global__ __launch_bounds__(256) void mlps_k(const float* __restrict__ emb,
    const float* __restrict__ wfc1, const float* __restrict__ wfc2,
    const float* __restrict__ wfcb,
    const int* __restrict__ i0, const int* __restrict__ i1,
    const int* __restrict__ i2,
    float* __restrict__ H1, float* __restrict__ H2, float* __restrict__ HB){
  __shared__ float sw[528];
  int b=blockIdx.x;
  const float* wfc; float* H; int eidx; bool ok;
  if (b<391){
    wfc=wfc1; H=H1;
    int e=b*256+threadIdx.x; ok=(e<N_EDGES); eidx= ok? e:0;
  } else if (b<782){
    wfc=wfc2; H=H2;
    int e=(b-391)*256+threadIdx.x; ok=(e<N_EDGES); eidx= ok? e:0;
  } else {
    wfc=wfcb; H=HB;
    int t=(b-782)*256+threadIdx.x; ok=(t<3*N_BONDS);
    eidx=0;
    if (ok){
      const int* ind = (t<N_BONDS)? i0 : (t<2*N_BONDS? i1 : i2);
      eidx = ind[t%N_BONDS];
    }
  }
  for(int t=threadIdx.x;t<528;t+=256) sw[t]=wfc[t];
  __syncthreads();
  if (!ok) return;
  int orow = (b<782)? eidx : ((b-782)*256+threadIdx.x);
  float h[16]; mlp16(emb[eidx], sw, h);
  float4* H4=(float4*)(H+(size_t)orow*16);
  #pragma unroll
  for(int q=0;q<4;++q) H4[q]=make_float4(h[4*q],h[4*q+1],h[4*q+2],h[4*q+3]);
}

// =====================================================================
// C[e x N] = 0.25 * A[idx(e) x 16] * B[16 x N]
// =====================================================================
__global__ __launch_bounds__(256) void gemm16_k(const float* __restrict__ A,
    const float* __restrict__ B, float* __restrict__ C, int Eloc, int N,
    const int* __restrict__ idx){
  __shared__ float As[64][16];
  int tid=threadIdx.x;
  int et=blockIdx.x, ct=blockIdx.y;
  for(int t=tid;t<64*16;t+=256){
    int r=t/16, i=t%16;
    int e=et*64+r;
    int ea=(e<Eloc)? (idx? idx[e]:e) : -1;
    As[r][i]=(ea>=0)? A[(size_t)ea*16+i] : 0.f;
  }
  __syncthreads();
  int col=ct*64+(tid&63);
  int eq=tid>>6;
  bool colok = col<N;
  float Breg[16];
  #pragma unroll
  for(int i=0;i<16;++i) Breg[i]= colok? B[(size_t)i*N+col]*0.25f : 0.f;
  #pragma unroll 4
  for(int es=0;es<16;++es){
    int e=et*64+eq*16+es;
    if (e>=Eloc) break;
    float acc=0.f;
    #pragma unroll
    for(int i=0;i<16;++i) acc+=As[eq*16+es][i]*Breg[i];
    if (colok) C[(size_t)e*N+col]=acc;
  }
}

// =====================================================================
// Edge conv 1: 8 lanes per node, 32 nodes/block.
// =====================================================================
__global__ __launch_bounds__(256) void edge1b_k(const float* __restrict__ x1,
    const float* __restrict__ sh, const float* __restrict__ ww1,
    const int* __restrict__ esrc, const int* __restrict__ sorted,
    const int* __restrict__ rowptr, const float* __restrict__ nnb,
    float* __restrict__ xout){
  int tid=threadIdx.x;
  int n=blockIdx.x*32 + (tid>>3);
  int w8=tid&7;
  if (n>=N_NODES) return;
  float inv = rsqrtf(nnb[0]);
  const float c = 0.70710678f*inv;
  float acc[9];
  #pragma unroll
  for(int t=0;t<9;++t) acc[t]=0.f;
  int r0=rowptr[n], r1=rowptr[n+1];
  for(int r=r0;r<r1;++r){
    int e=sorted[r];
    int src=esrc[e];
    float a0=x1[2*src], a1=x1[2*src+1];
    const float* wr=ww1+(size_t)r*48;
    float w0=wr[w8],    w1=wr[8+w8];
    float w2=wr[16+w8], w3=wr[24+w8];
    float w4=wr[32+w8], w5=wr[40+w8];
    const float* b=sh+(size_t)e*9;
    float s0=w0*a0+w1*a1;
    acc[0]+=s0*b[0];
    float s1=w2*a0+w3*a1;
    #pragma unroll
    for(int j=0;j<3;++j) acc[1+j]+=s1*b[1+j];
    float s2=w4*a0+w5*a1;
    #pragma unroll
    for(int j=0;j<5;++j) acc[4+j]+=s2*b[4+j];
  }
  float* o=xout+(size_t)n*72;
  o[w8]=acc[0]*c;
  #pragma unroll
  for(int j=0;j<3;++j) o[8+w8*3+j]=acc[1+j]*c;
  #pragma unroll
  for(int j=0;j<5;++j) o[32+w8*5+j]=acc[4+j]*c;
}

// =====================================================================
// Block-diagonal linears, LDS-staged
// =====================================================================
__global__ __launch_bounds__(256) void lin2b_k(float* __restrict__ x, const float* __restrict__ w){
  __shared__ float sX[32*72];
  __shared__ float sW[192];
  int tid=threadIdx.x;
  int base=blockIdx.x*32;
  if (tid<192) sW[tid]=w[tid];
  for(int t=tid;t<32*72;t+=256){
    int n=base+t/72;
    sX[t] = (n<N_NODES)? x[(size_t)n*72 + t%72] : 0.f;
  }
  __syncthreads();
  int ns=tid>>3, v=tid&7;
  const float r8=0.35355339f;
  const float* X=sX+ns*72;
  float r[9];
  {
    float a=0.f;
    #pragma unroll
    for(int u=0;u<8;++u) a+=X[u]*sW[u*8+v];
    r[0]=tanhf(a*r8);
  }
  #pragma unroll
  for(int i=0;i<3;++i){
    float a=0.f;
    #pragma unroll
    for(int u=0;u<8;++u) a+=X[8+u*3+i]*sW[64+u*8+v];
    r[1+i]=a*r8;
  }
  #pragma unroll
  for(int i=0;i<5;++i){
    float a=0.f;
    #pragma unroll
    for(int u=0;u<8;++u) a+=X[32+u*5+i]*sW[128+u*8+v];
    r[4+i]=a*r8;
  }
  __syncthreads();
  float* Xw=sX+ns*72;
  Xw[v]=r[0];
  #pragma unroll
  for(int i=0;i<3;++i) Xw[8+v*3+i]=r[1+i];
  #pragma unroll
  for(int i=0;i<5;++i) Xw[32+v*5+i]=r[4+i];
  __syncthreads();
  for(int t=tid;t<32*72;t+=256){
    int n=base+t/72;
    if (n<N_NODES) x[(size_t)n*72 + t%72]=sX[t];
  }
}

__global__ __launch_bounds__(256) void lin3b_k(float* __restrict__ x, const float* __restrict__ w){
  __shared__ float sX[32*144];
  __shared__ float sW[384];
  int tid=threadIdx.x;
  int base=blockIdx.x*32;
  for(int t=tid;t<384;t+=256) sW[t]=w[t];
  for(int t=tid;t<32*144;t+=256){
    int n=base+t/144;
    sX[t] = (n<N_NODES)? x[(size_t)n*144 + t%144] : 0.f;
  }
  __syncthreads();
  int ns=tid>>3, v=tid&7;
  const float r8=0.35355339f;
  const float* X=sX+ns*144;
  float r[18];
  {
    float a=0.f;
    #pragma unroll
    for(int u=0;u<8;++u) a+=X[u]*sW[u*8+v];
    r[0]=tanhf(a*r8);
  }
  {
    float a=0.f;
    #pragma unroll
    for(int u=0;u<8;++u) a+=X[8+u]*sW[64+u*8+v];
    r[1]=tanhf(a*r8);
  }
  #pragma unroll
  for(int i=0;i<3;++i){
    float a=0.f;
    #pragma unroll
    for(int u=0;u<8;++u) a+=X[16+u*3+i]*sW[128+u*8+v];
    r[2+i]=a*r8;
  }
  #pragma unroll
  for(int i=0;i<3;++i){
    float a=0.f;
    #pragma unroll
    for(int u=0;u<8;++u) a+=X[40+u*3+i]*sW[192+u*8+v];
    r[5+i]=a*r8;
  }
  #pragma unroll
  for(int i=0;i<5;++i){
    float a=0.f;
    #pragma unroll
    for(int u=0;u<8;++u) a+=X[64+u*5+i]*sW[256+u*8+v];
    r[8+i]=a*r8;
  }
  #pragma unroll
  for(int i=0;i<5;++i){
    float a=0.f;
    #pragma unroll
    for(int u=0;u<8;++u) a+=X[104+u*5+i]*sW[320+u*8+v];
    r[13+i]=a*r8;
  }
  __syncthreads();
  float* Xw=sX+ns*144;
  Xw[v]=r[0];
  Xw[8+v]=r[1];
  #pragma unroll
  for(int i=0;i<3;++i) Xw[16+v*3+i]=r[2+i];
  #pragma unroll
  for(int i=0;i<3;++i) Xw[40+v*3+i]=r[5+i];
  #pragma unroll
  for(int i=0;i<5;++i) Xw[64+v*5+i]=r[8+i];
  #pragma unroll
  for(int i=0;i<5;++i) Xw[104+v*5+i]=r[13+i];
  __syncthreads();
  for(int t=tid;t<32*144;t+=256){
    int n=base+t/144;
    if (n<N_NODES) x[(size_t)n*144 + t%144]=sX[t];
  }
}

// =====================================================================
// TP path accumulate — compile-time sparsity via cg_nz
// =====================================================================
template<int L1,int L2,int LO,int BO,int SLOT>
__device__ __forceinline__ void tp_acc(const float* Au, const float* b,
    const float* __restrict__ cg, float wv, float* acc){
  constexpr int D1=2*L1+1, D2=2*L2+1, DN=2*LO+1;
  const float* C = cg + ((L1*3+L2)*3+LO)*125;
  float P[DN];
  #pragma unroll
  for(int k=0;k<DN;++k) P[k]=0.f;
  #pragma unroll
  for(int i=0;i<D1;++i){
    float av=Au[i];
    #pragma unroll
    for(int j=0;j<D2;++j){
      #pragma unroll
      for(int k=0;k<DN;++k){
        if (cg_nz(L1,L2,LO,i,j,k)){
          float cv=C[(i*D2+j)*DN+k];
          P[k]+=av*(cv*b[BO+j]);
        }
      }
    }
  }
  #pragma unroll
  for(int k=0;k<DN;++k) acc[SLOT+k]+=wv*P[k];
}

// full-node finish: direct write (fallback kernel only)
__device__ __forceinline__ void e2_finish2(float* acc, float inv, float* __restrict__ o, bool first){
  int lane=threadIdx.x&63;
  int w=lane&7;
  #pragma unroll
  for(int t=0;t<18;++t){
    acc[t]+=__shfl_xor(acc[t],8,64);
    acc[t]+=__shfl_xor(acc[t],16,64);
    acc[t]+=__shfl_xor(acc[t],32,64);
  }
  if (lane<8){
    float f0 =rsqrtf(24.f)*inv;
    float f1e=rsqrtf(16.f)*inv;
    float f1o=rsqrtf(32.f)*inv;
    float f2e=rsqrtf(32.f)*inv;
    float f2o=rsqrtf(16.f)*inv;
    if (first){
      o[0+w]=acc[0]*f0;
      o[8+w]=0.f;
      #pragma unroll
      for(int k=0;k<3;++k) o[16+w*3+k]=acc[2+k]*f1e;
      #pragma unroll
      for(int k=0;k<3;++k) o[40+w*3+k]=acc[5+k]*f1o;
      #pragma unroll
      for(int k=0;k<5;++k) o[64+w*5+k]=acc[8+k]*f2e;
      #pragma unroll
      for(int k=0;k<5;++k) o[104+w*5+k]=acc[13+k]*f2o;
    } else {
      o[0+w]+=acc[0]*f0;
      #pragma unroll
      for(int k=0;k<3;++k) o[16+w*3+k]+=acc[2+k]*f1e;
      #pragma unroll
      for(int k=0;k<3;++k) o[40+w*3+k]+=acc[5+k]*f1o;
      #pragma unroll
      for(int k=0;k<5;++k) o[64+w*5+k]+=acc[8+k]*f2e;
      #pragma unroll
      for(int k=0;k<5;++k) o[104+w*5+k]+=acc[13+k]*f2o;
    }
  }
}

// partial-node flush: atomic accumulate (row-parallel kernel)
__device__ __forceinline__ void e2_flush(float* acc, float inv, float* __restrict__ o){
  int lane=threadIdx.x&63;
  int w=lane&7;
  #pragma unroll
  for(int t=0;t<18;++t){
    acc[t]+=__shfl_xor(acc[t],8,64);
    acc[t]+=__shfl_xor(acc[t],16,64);
    acc[t]+=__shfl_xor(acc[t],32,64);
  }
  if (lane<8){
    float f0 =rsqrtf(24.f)*inv;
    float f1e=rsqrtf(16.f)*inv;
    float f1o=rsqrtf(32.f)*inv;
    float f2e=rsqrtf(32.f)*inv;
    float f2o=rsqrtf(16.f)*inv;
    atomicAdd(&o[0+w], acc[0]*f0);
    #pragma unroll
    for(int k=0;k<3;++k) atomicAdd(&o[16+w*3+k], acc[2+k]*f1e);
    #pragma unroll
    for(int k=0;k<3;++k) atomicAdd(&o[40+w*3+k], acc[5+k]*f1o);
    #pragma unroll
    for(int k=0;k<5;++k) atomicAdd(&o[64+w*5+k], acc[8+k]*f2e);
    #pragma unroll
    for(int k=0;k<5;++k) atomicAdd(&o[104+w*5+k], acc[13+k]*f2o);
  }
}

// shared TP-consume (weights from any address space, offsets in floats)
__device__ __forceinline__ void e2c_consume(const float* __restrict__ xn,
    const float* __restrict__ sh, const float* __restrict__ cg,
    const float* wwp, int e, int src, int u, int lane, float* acc){
  float sv[15];
  sv[ 0]=wwp[  0+lane]; sv[ 1]=wwp[256+lane]; sv[ 2]=wwp[768+lane];
  sv[ 3]=wwp[320+lane]; sv[ 4]=wwp[832+lane];
  sv[ 5]=wwp[ 64+lane]; sv[ 6]=wwp[192+lane]; sv[ 7]=wwp[448+lane]; sv[ 8]=wwp[640+lane];
  sv[ 9]=wwp[128+lane]; sv[10]=wwp[384+lane]; sv[11]=wwp[576+lane]; sv[12]=wwp[896+lane];
  sv[13]=wwp[512+lane]; sv[14]=wwp[704+lane];
  const float* A = xn + (size_t)src*72;
  float b[9];
  #pragma unroll
  for(int j=0;j<9;++j) b[j]=sh[(size_t)e*9+j];
  float a0[1]; a0[0]=A[u];
  float a1[3];
  #pragma unroll
  for(int i=0;i<3;++i) a1[i]=A[8+u*3+i];
  float a2[5];
  #pragma unroll
  for(int i=0;i<5;++i) a2[i]=A[32+u*5+i];
  tp_acc<0,0,0,0, 0>(a0,b,cg,sv[ 0],acc);
  tp_acc<1,1,0,1, 0>(a1,b,cg,sv[ 1],acc);
  tp_acc<2,2,0,4, 0>(a2,b,cg,sv[ 2],acc);
  tp_acc<1,1,1,1, 2>(a1,b,cg,sv[ 3],acc);
  tp_acc<2,2,1,4, 2>(a2,b,cg,sv[ 4],acc);
  tp_acc<0,1,1,1, 5>(a0,b,cg,sv[ 5],acc);
  tp_acc<1,0,1,0, 5>(a1,b,cg,sv[ 6],acc);
  tp_acc<1,2,1,4, 5>(a1,b,cg,sv[ 7],acc);
  tp_acc<2,1,1,1, 5>(a2,b,cg,sv[ 8],acc);
  tp_acc<0,2,2,4, 8>(a0,b,cg,sv[ 9],acc);
  tp_acc<1,1,2,1, 8>(a1,b,cg,sv[10],acc);
  tp_acc<2,0,2,0, 8>(a2,b,cg,sv[11],acc);
  tp_acc<2,2,2,4, 8>(a2,b,cg,sv[12],acc);
  tp_acc<1,2,2,4,13>(a1,b,cg,sv[13],acc);
  tp_acc<2,1,2,1,13>(a2,b,cg,sv[14],acc);
}

// =====================================================================
// Edge conv 2 PRIMARY (row-parallel): wave handles RPW CSR rows of the
// chunk [rb,re); binary-search start node; per-node register acc; on
// node boundary flush via atomicAdd into pre-zeroed xout.
// =====================================================================
__global__ __launch_bounds__(256) void edge2r_k(const float* __restrict__ xn,
    const float* __restrict__ sh, const float* __restrict__ ww2,
    const int* __restrict__ esrc, const int* __restrict__ sorted,
    const int* __restrict__ rowptr, const float* __restrict__ nnb,
    const float* __restrict__ cg, float* __restrict__ xout,
    int rb, int re){
  int gw=blockIdx.x*4+(threadIdx.x>>6);
  int lane=threadIdx.x&63;
  int u=lane>>3;
  int rs=rb+gw*RPW;
  if (rs>=re) return;
  int rend=min(rs+RPW, re);
  float inv=rsqrtf(nnb[0]);
  // largest n with rowptr[n] <= rs  (handles empty nodes correctly)
  int lo=0, hi=N_NODES-1;
  while(lo<hi){ int mid=(lo+hi+1)>>1; if(rowptr[mid]<=rs) lo=mid; else hi=mid-1; }
  int n=lo;
  int nend=rowptr[n+1];
  float acc[18];
  #pragma unroll
  for(int t=0;t<18;++t) acc[t]=0.f;
  bool dirty=false;
  for(int r=rs;r<rend;++r){
    while(r>=nend){
      if (dirty){
        e2_flush(acc, inv, xout+(size_t)n*144);
        #pragma unroll
        for(int t=0;t<18;++t) acc[t]=0.f;
        dirty=false;
      }
      n++; nend=rowptr[n+1];
    }
    int e=__builtin_amdgcn_readfirstlane(sorted[r]);
    int src=__builtin_amdgcn_readfirstlane(esrc[e]);
    e2c_consume(xn,sh,cg, ww2+(size_t)(r-rb)*960, e,src,u,lane,acc);
    dirty=true;
  }
  if (dirty) e2_flush(acc, inv, xout+(size_t)n*144);
}

// =====================================================================
// Edge conv 2 FALLBACK (tiny workspace): cooperative per-edge ww-GEMM
// =====================================================================
__global__ __launch_bounds__(256) void edge2c_k(const float* __restrict__ xn,
    const float* __restrict__ sh, const float* __restrict__ h2,
    const float* __restrict__ Wg, const int* __restrict__ esrc,
    const int* __restrict__ sorted, const int* __restrict__ rowptr,
    const float* __restrict__ nnb, const float* __restrict__ cg,
    float* __restrict__ xout){
  __shared__ float ww[2][4][960];
  __shared__ int sE[4];
  __shared__ int sCnt[4];
  int tid=threadIdx.x, wid=tid>>6, lane=tid&63;
  int n=blockIdx.x*4+wid;
  int u=lane>>3;
  float inv=rsqrtf(nnb[0]);
  int r0=rowptr[n], r1=rowptr[n+1];
  if (lane==0) sCnt[wid]=r1-r0;
  __syncthreads();
  int mx = max(max(sCnt[0],sCnt[1]),max(sCnt[2],sCnt[3]));
  float acc[18];
  #pragma unroll
  for(int t=0;t<18;++t) acc[t]=0.f;
  int pe=0, psrc=0; bool pact=false;
  for(int t=0;t<mx;++t){
    int r=r0+t;
    bool act=(r<r1);
    int e=0, src=0;
    if (act){
      e=__builtin_amdgcn_readfirstlane(sorted[r]);
      src=__builtin_amdgcn_readfirstlane(esrc[e]);
    }
    if (lane==0) sE[wid]= act? e : -1;
    __syncthreads();
    if (tid<240){
      int e0=max(sE[0],0), e1=max(sE[1],0), e2i=max(sE[2],0), e3=max(sE[3],0);
      const float* h0=h2+(size_t)e0*16;
      const float* h1=h2+(size_t)e1*16;
      const float* hq=h2+(size_t)e2i*16;
      const float* h3=h2+(size_t)e3*16;
      float4 av[4];
      #pragma unroll
      for(int k=0;k<4;++k) av[k]=make_float4(0.f,0.f,0.f,0.f);
      #pragma unroll
      for(int i=0;i<16;++i){
        float hx=h0[i], hy=h1[i], hz=hq[i], hw=h3[i];
        const float* Wr=Wg+i*960;
        #pragma unroll
        for(int k=0;k<4;++k){
          float w=Wr[tid+240*k];
          av[k].x+=hx*w; av[k].y+=hy*w; av[k].z+=hz*w; av[k].w+=hw*w;
        }
      }
      float* wb=&ww[t&1][0][0];
      #pragma unroll
      for(int k=0;k<4;++k){
        int c=tid+240*k;
        wb[c]=av[k].x*0.25f; wb[960+c]=av[k].y*0.25f;
        wb[1920+c]=av[k].z*0.25f; wb[2880+c]=av[k].w*0.25f;
      }
    }
    if (pact){
      const float* wwp=&ww[(t&1)^1][wid][0];
      e2c_consume(xn,sh,cg,wwp,pe,psrc,u,lane,acc);
    }
    pe=e; psrc=src; pact=act;
    __syncthreads();
  }
  if (pact){
    const float* wwp=&ww[(mx-1)&1][wid][0];
    e2c_consume(xn,sh,cg,wwp,pe,psrc,u,lane,acc);
  }
  e2_finish2(acc, inv, xout+(size_t)n*144, true);
}

// =====================================================================
// Irrep linear with input-slice range + optional zero-fill
// =====================================================================
struct IrS{ short off,m,l,p; };
__device__ const IrS SL_MID2[6]={{0,8,0,1},{8,8,0,-1},{16,8,1,1},{40,8,1,-1},{64,8,2,1},{104,8,2,-1}};
__device__ const IrS SL_HH[6]={{0,4,0,1},{4,2,1,-1},{10,2,1,-1},{16,1,0,1},{17,1,1,1},{20,1,2,1}};
__device__ const IrS SL_CC[34]={{0,9,0,1},{9,6,1,-1},{27,3,2,1},{42,6,1,-1},
 {60,1,0,1},{61,1,1,1},{64,1,2,1},{69,1,0,1},{70,1,1,1},{73,1,2,1},
 {78,1,0,1},{79,1,1,1},{82,1,2,1},{87,1,0,1},{88,1,1,1},{91,1,2,1},
 {96,1,1,-1},{99,1,2,-1},{104,1,3,-1},{111,1,1,-1},{114,1,2,-1},{119,1,3,-1},
 {126,3,2,1},{141,1,1,-1},{144,1,2,-1},{149,1,3,-1},{156,1,1,-1},{159,1,2,-1},{164,1,3,-1},
 {171,1,0,1},{172,1,1,1},{175,1,2,1},{180,1,3,1},{187,1,4,1}};
__device__ const IrS SL_CH[13]={{0,6,0,1},{6,3,1,-1},{15,4,1,-1},{27,1,0,1},{28,1,1,1},{31,1,2,1},
 {36,1,0,1},{37,1,1,1},{40,1,2,1},{45,2,2,1},{55,1,1,-1},{58,1,2,-1},{63,1,3,-1}};

__device__ void lin_out_r(const float* __restrict__ x, bool act16, const float* __restrict__ w,
                          const IrS* so, int no, void* out, size_t base, bool f32o,
                          float scale, int aBeg, int aEnd, bool zf){
  float tx[16];
  bool need_tx = act16 && (aBeg<2);
  if (need_tx){
    #pragma unroll
    for(int i=0;i<16;++i) tx[i]=tanhf(x[i]);
  }
  if (zf){
    for(int bI=0;bI<no;++bI){
      if (so[bI].l>=3){
        int cnt=so[bI].m*(2*so[bI].l+1);
        for(int t=0;t<cnt;++t) stout(out, base+so[bI].off+t, 0.f, f32o);
      }
    }
  }
  int woff=0;
  float f = 0.35355339f*scale;
  for(int a=0;a<6;++a){
    int la=SL_MID2[a].l, pa=SL_MID2[a].p, oa=SL_MID2[a].off;
    int d=2*la+1;
    bool doit = (a>=aBeg && a<aEnd);
    for(int bI=0;bI<no;++bI){
      if (so[bI].l!=la || so[bI].p!=pa) continue;
      int mo=so[bI].m;
      if (doit){
        for(int v=0;v<mo;++v){
          for(int i=0;i<d;++i){
            float acc=0.f;
            for(int u=0;u<8;++u){
              int idx=oa+u*d+i;
              float xv=(act16 && idx<16)? tx[idx] : x[idx];
              acc+=xv*w[woff+u*mo+v];
            }
            stout(out, base+so[bI].off+v*d+i, acc*f, f32o);
          }
        }
      }
      woff+=8*mo;
    }
  }
}

// =====================================================================
// Node outputs: WAVE-level job split.
// =====================================================================
__global__ __launch_bounds__(256) void node_out_k(const float* __restrict__ x,
    const float* __restrict__ wC, const float* __restrict__ wH,
    const float* __restrict__ ws1, const float* __restrict__ ws2,
    void* out, const int* __restrict__ flag){
  int tid=threadIdx.x;
  int gw=blockIdx.x*4+(tid>>6);
  int lane=tid&63;
  int job=gw&7;
  int n=(gw>>3)*64+lane;
  if (n>=N_NODES) return;
  bool f32o = (*flag)!=0;
  const float* X = x + (size_t)n*144;
  if (job==0){
    lin_out_r(X,false,wH,SL_HH,6, out, (size_t)n*25, f32o, 0.2f, 0,6, true);
  } else if (job==1){
    const float r8=0.35355339f, r32=0.17677670f;
    float t0[32];
    for(int v=0;v<32;++v){
      float acc=0.f;
      #pragma unroll
      for(int u=0;u<8;++u) acc+=X[u]*ws1[u*32+v];
      t0[v]=tanhf(acc*r8);
    }
    float t2[5];
    #pragma unroll
    for(int i=0;i<5;++i){
      float acc=0.f;
      #pragma unroll
      for(int u=0;u<8;++u) acc+=X[64+u*5+i]*ws1[256+u];
      t2[i]=acc*r8;
    }
    size_t sb = 2501000 + (size_t)n*6;
    float acc=0.f;
    for(int v=0;v<32;++v) acc+=t0[v]*ws2[v];
    stout(out, sb, acc*r32, f32o);
    float w2e=ws2[32];
    #pragma unroll
    for(int i=0;i<5;++i) stout(out, sb+1+i, t2[i]*w2e, f32o);
  } else {
    int a=job-2;
    lin_out_r(X,false,wC,SL_CC,34, out, 250000 + (size_t)n*196, f32o, 0.2f,
              a, a+1, a==0);
  }
}

// =====================================================================
// Bond TP (R8 scalar form): one wave per bond, 60 paths, cooperative
// ww-GEMM double-buffered, direct store.
// =====================================================================
template<int L1,int L2,int LO>
__device__ __forceinline__ void bond_path2(const float* sa,int ao,const float* sb,int bo,
    const float* __restrict__ cg, const float* __restrict__ wwp,
    float invfan, float* sF, int oo, int lane){
  constexpr int D1=2*L1+1, D2=2*L2+1, DN=2*LO+1;
  const float* C = cg + ((L1*3+L2)*3+LO)*125;
  int u=lane>>3, v=lane&7;
  float P[DN];
  #pragma unroll
  for(int k=0;k<DN;++k) P[k]=0.f;
  #pragma unroll
  for(int i=0;i<D1;++i){
    float avv=sa[ao+u*D1+i];
    #pragma unroll
    for(int j=0;j<D2;++j){
      #pragma unroll
      for(int k=0;k<DN;++k){
        if (cg_nz(L1,L2,LO,i,j,k)){
          float cv=C[(i*D2+j)*DN+k];
          P[k]+=(avv*sb[bo+v*D2+j])*cv;
        }
      }
    }
  }
  int v2=u;
  float acc[DN];
  #pragma unroll
  for(int k=0;k<DN;++k) acc[k]=0.f;
  #pragma unroll
  for(int u2=0;u2<8;++u2){
    float ww=wwp[u2*64 + lane];
    int srcl=u2*8+v2;
    #pragma unroll
    for(int k=0;k<DN;++k) acc[k]+=ww*__shfl(P[k],srcl,64);
  }
  #pragma unroll
  for(int k=0;k<DN;++k){
    acc[k]+=__shfl_xor(acc[k],8,64);
    acc[k]+=__shfl_xor(acc[k],16,64);
    acc[k]+=__shfl_xor(acc[k],32,64);
  }
  int w=lane&7;
  if (v2==0){
    #pragma unroll
    for(int k=0;k<DN;++k) sF[oo+w*DN+k]+=acc[k]*invfan;
  }
}

__device__ __forceinline__ void bond_disp(int code, const float* a,int ao,const float* bb,int bo,
    const float* __restrict__ cg, const float* __restrict__ wwp,
    float fv, float* Ff, int oo, int lane){
  switch(code){
    case 0:  bond_path2<0,0,0>(a,ao,bb,bo,cg,wwp,fv,Ff,oo,lane); break;
    case 4:  bond_path2<0,1,1>(a,ao,bb,bo,cg,wwp,fv,Ff,oo,lane); break;
    case 8:  bond_path2<0,2,2>(a,ao,bb,bo,cg,wwp,fv,Ff,oo,lane); break;
    case 10: bond_path2<1,0,1>(a,ao,bb,bo,cg,wwp,fv,Ff,oo,lane); break;
    case 12: bond_path2<1,1,0>(a,ao,bb,bo,cg,wwp,fv,Ff,oo,lane); break;
    case 13: bond_path2<1,1,1>(a,ao,bb,bo,cg,wwp,fv,Ff,oo,lane); break;
    case 14: bond_path2<1,1,2>(a,ao,bb,bo,cg,wwp,fv,Ff,oo,lane); break;
    case 16: bond_path2<1,2,1>(a,ao,bb,bo,cg,wwp,fv,Ff,oo,lane); break;
    case 17: bond_path2<1,2,2>(a,ao,bb,bo,cg,wwp,fv,Ff,oo,lane); break;
    case 20: bond_path2<2,0,2>(a,ao,bb,bo,cg,wwp,fv,Ff,oo,lane); break;
    case 22: bond_path2<2,1,1>(a,ao,bb,bo,cg,wwp,fv,Ff,oo,lane); break;
    case 23: bond_path2<2,1,2>(a,ao,bb,bo,cg,wwp,fv,Ff,oo,lane); break;
    case 24: bond_path2<2,2,0>(a,ao,bb,bo,cg,wwp,fv,Ff,oo,lane); break;
    case 25: bond_path2<2,2,1>(a,ao,bb,bo,cg,wwp,fv,Ff,oo,lane); break;
    case 26: bond_path2<2,2,2>(a,ao,bb,bo,cg,wwp,fv,Ff,oo,lane); break;
  }
}

__global__ __launch_bounds__(256) void bond_tpl_k(const float* __restrict__ xn,
    const float* __restrict__ hb, const float* __restrict__ Wg,
    const int* __restrict__ esrc, const int* __restrict__ edst,
    const int* __restrict__ i0, const int* __restrict__ i1,
    const int* __restrict__ i2, const float* __restrict__ cg,
    float* __restrict__ F0, float* __restrict__ F1, float* __restrict__ F2){
  __shared__ float sA[4][144], sB[4][144], sF[4][144];
  __shared__ float ww[2][2048];
  int tid=threadIdx.x;
  int wid=tid>>6, lane=tid&63;
  int gb=blockIdx.x*4+wid;
  int s=gb/N_BONDS, bi=gb-s*N_BONDS;
  const int* ind=(s==0)?i0:(s==1)?i1:i2;
  float* F=(s==0)?F0:(s==1)?F1:F2;
  int ie=ind[bi];
  int src=esrc[ie], dst=edst[ie];
  for(int t=lane;t<144;t+=64){
    sA[wid][t]=xn[(size_t)src*144+t];
    sB[wid][t]=xn[(size_t)dst*144+t];
    sF[wid][t]=0.f;
  }
  float4 hreg[16];
  {
    size_t hbase=(size_t)blockIdx.x*64;
    #pragma unroll
    for(int i=0;i<16;++i)
      hreg[i]=make_float4(hb[hbase+i],hb[hbase+16+i],hb[hbase+32+i],hb[hbase+48+i]);
  }
  const int SL_L[6]={0,0,1,1,2,2};
  const int SL_P[6]={1,-1,1,-1,1,-1};
  const int SL_O[6]={0,8,16,40,64,104};
  const float fi0=rsqrtf(384.f), fi1=rsqrtf(768.f);
  int pidx=0;
  int pcode=0, pao=0, pbo=0, poo=0; float pfv=0.f;
  for(int s1=0;s1<6;++s1){
    for(int s2=0;s2<6;++s2){
      for(int so=0;so<6;++so){
        int l1=SL_L[s1], l2=SL_L[s2], lo=SL_L[so];
        if (SL_P[so]!=SL_P[s1]*SL_P[s2]) continue;
        if (lo<iabs(l1-l2) || lo>l1+l2) continue;
        {
          const float* Wp = Wg + (size_t)pidx*512;
          float4 a0=make_float4(0.f,0.f,0.f,0.f);
          float4 a1=make_float4(0.f,0.f,0.f,0.f);
          #pragma unroll
          for(int i=0;i<16;++i){
            float w0=Wp[(size_t)i*30720 + tid];
            float w1=Wp[(size_t)i*30720 + tid + 256];
            float4 h=hreg[i];
            a0.x+=h.x*w0; a0.y+=h.y*w0; a0.z+=h.z*w0; a0.w+=h.w*w0;
            a1.x+=h.x*w1; a1.y+=h.y*w1; a1.z+=h.z*w1; a1.w+=h.w*w1;
          }
          float* wb=ww[pidx&1];
          wb[0*512+tid]    =a0.x*0.25f;
          wb[1*512+tid]    =a0.y*0.25f;
          wb[2*512+tid]    =a0.z*0.25f;
          wb[3*512+tid]    =a0.w*0.25f;
          wb[0*512+tid+256]=a1.x*0.25f;
          wb[1*512+tid+256]=a1.y*0.25f;
          wb[2*512+tid+256]=a1.z*0.25f;
          wb[3*512+tid+256]=a1.w*0.25f;
        }
        if (pidx>0){
          const float* wwp = ww[(pidx-1)&1] + wid*512;
          bond_disp(pcode, sA[wid], pao, sB[wid], pbo, cg, wwp, pfv, sF[wid], poo, lane);
        }
        pcode=l1*9+l2*3+lo; pao=SL_O[s1]; pbo=SL_O[s2]; poo=SL_O[so];
        pfv=(lo==0)? fi0 : fi1;
        pidx++;
        __syncthreads();
      }
    }
  }
  {
    const float* wwp = ww[(pidx-1)&1] + wid*512;
    bond_disp(pcode, sA[wid], pao, sB[wid], pbo, cg, wwp, pfv, sF[wid], poo, lane);
  }
  __syncthreads();
  for(int t=lane;t<144;t+=64) F[(size_t)bi*144+t]=sF[wid][t];
}

// =====================================================================
// Bond outputs: single fused launch, WAVE-level job split.
// =====================================================================
__global__ __launch_bounds__(256) void bond_out3_k(
    const float* __restrict__ F0, const float* __restrict__ F1,
    const float* __restrict__ F2,
    const float* __restrict__ wHH, const float* __restrict__ wCC,
    const float* __restrict__ wCH,
    const float* __restrict__ wg1, const float* __restrict__ wg2,
    void* out, const int* __restrict__ flag){
  int tbl=blockIdx.x>>5;
  int blk=blockIdx.x&31;
  int tid=threadIdx.x;
  int gw=blk*4+(tid>>6);
  int lane=tid&63;
  int job=gw&7;
  int n=(gw>>3)*64+lane;
  if (n>=N_BONDS) return;
  bool f32o = (*flag)!=0;
  const float* F = (tbl==0)?F0:(tbl==1)?F1:F2;
  const float* wlin = (tbl==0)?wHH:(tbl==1)?wCC:wCH;
  size_t baseE = (tbl==0)?2210000u:(tbl==1)?2305000u:2235000u;
  size_t baseG = (tbl==0)?2564000u:(tbl==1)?2561000u:2567000u;
  const float* X=F+(size_t)n*144;
  if (job==0){
    const float r8=0.35355339f, r32=0.17677670f;
    float g[32];
    for(int v=0;v<32;++v){
      float acc=0.f;
      #pragma unroll
      for(int u=0;u<8;++u) acc+=X[u]*wg1[u*32+v];
      g[v]=tanhf(acc*r8);
    }
    #pragma unroll
    for(int c=0;c<3;++c){
      float acc=0.f;
      for(int v=0;v<32;++v) acc+=g[v]*wg2[v*3+c];
      stout(out, baseG+(size_t)n*3+c, acc*r32, f32o);
    }
  } else if (job>=2){
    const IrS* so; int no; int dim;
    if(tbl==0){so=SL_HH;no=6;dim=25;}
    else if(tbl==1){so=SL_CC;no=34;dim=196;}
    else {so=SL_CH;no=13;dim=70;}
    int a=job-2;
    lin_out_r(X,true,wlin,so,no,out,baseE+(size_t)n*dim,f32o,0.2f,
              a, a+1, a==0);
  }
}

// =====================================================================
extern "C" void kernel_launch(void* const* d_in, const int* in_sizes, int n_in,
                              void* d_out, int out_size, void* d_ws, size_t ws_size,
                              hipStream_t stream){
  const int* esrc=(const int*)d_in[19];
  const int* edst=(const int*)d_in[20];
  const int* iHH =(const int*)d_in[21];
  const int* iCC =(const int*)d_in[22];
  const int* iCH =(const int*)d_in[23];
  float* ws=(float*)d_ws;
  int* flag=(int*)d_ws;

  size_t off=16;
  auto alloc=[&](size_t n){ size_t o=off; off+=(n+15)&~(size_t)15; return o; };
  size_t o_cg = alloc(27*125);
  size_t o_st[19];
  for(int i=0;i<19;++i) o_st[i]=alloc((size_t)in_sizes[i]);
  size_t o_xM1 = alloc(720000);
  size_t o_xM2 = alloc(1440000);
  size_t o_h2  = alloc((size_t)N_EDGES*16);
  size_t o_hb  = alloc((size_t)3*N_BONDS*16);
  size_t o_cnt = alloc(10016);
  size_t o_rp  = alloc(10016);
  size_t o_pos = alloc(10016);
  size_t o_srt = alloc(N_EDGES);
  // TAIL: everything below is dead during edge conv 2 -> reused as ww2
  size_t o_x1  = alloc(20000);
  size_t o_F0  = alloc(144000);
  size_t o_F1  = alloc(144000);
  size_t o_F2  = alloc(144000);
  size_t o_h1  = alloc((size_t)N_EDGES*16);
  size_t o_ww1 = alloc((size_t)N_EDGES*48);
  (void)o_ww1;

  float* cg  = ws+o_cg;
  float* x1  = ws+o_x1;
  float* xM1 = ws+o_xM1;
  float* xM2 = ws+o_xM2;
  float* F0  = ws+o_F0;
  float* F1  = ws+o_F1;
  float* F2  = ws+o_F2;
  float* h1  = ws+o_h1;
  float* h2  = ws+o_h2;
  float* hb  = ws+o_hb;
  float* ww1 = ws+o_ww1;
  int* cnt   = (int*)(ws+o_cnt);
  int* rowptr= (int*)(ws+o_rp);
  int* pos   = (int*)(ws+o_pos);
  int* sorted= (int*)(ws+o_srt);

  // ww2 reuses x1+F+h1+ww1+slack (all dead during edge conv 2)
  size_t totf = ws_size/sizeof(float);
  size_t availf = (totf>o_x1)? totf-o_x1 : 0;
  int CHUNK = (int)((availf/960 < (size_t)N_EDGES)? availf/960 : (size_t)N_EDGES);
  bool use_chunk = (CHUNK >= 2000);
  float* ww2 = ws + o_x1;

  CvtArgs ca;
  for(int i=0;i<19;++i){ ca.src[i]=d_in[i]; ca.dst[i]=ws+o_st[i]; ca.n[i]=in_sizes[i]; }
  const float* f_in   = ws+o_st[0];
  const float* sh     = ws+o_st[1];
  const float* emb    = ws+o_st[2];
  const float* nnb    = ws+o_st[3];
  const float* w_lin1 = ws+o_st[4];
  const float* w_lin2 = ws+o_st[5];
  const float* w_lin3 = ws+o_st[6];
  const float* w_linCC= ws+o_st[7];
  const float* w_linHH= ws+o_st[8];
  const float* w_linCH= ws+o_st[9];
  const float* w_linC = ws+o_st[10];
  const float* w_linH = ws+o_st[11];
  const float* w_s1   = ws+o_st[12];
  const float* w_s2   = ws+o_st[13];
  const float* w_g1   = ws+o_st[14];
  const float* w_g2   = ws+o_st[15];
  const float* w_fc1  = ws+o_st[16];
  const float* w_fc2  = ws+o_st[17];
  const float* w_fcb  = ws+o_st[18];

  convert_k<<<512,256,0,stream>>>(ca, (const unsigned short*)d_in[3], flag);
  cg_init_k<<<27,128,0,stream>>>(cg);
  // CSR by destination
  hipMemsetAsync(cnt, 0, 10000*sizeof(int), stream);
  csr_count_k<<<391,256,0,stream>>>(edst, cnt);
  csr_scan_k<<<1,256,0,stream>>>(cnt, rowptr, pos);
  csr_scatter_k<<<391,256,0,stream>>>(edst, pos, sorted);

  nodeA_k<<<40,256,0,stream>>>(f_in,w_lin1,x1);
  mlps_k<<<794,256,0,stream>>>(emb, w_fc1, w_fc2, w_fcb, iHH, iCC, iCH, h1, h2, hb);

  // edge conv 1
  gemm16_k<<<dim3(1563,1),256,0,stream>>>(h1, w_fc1+528, ww1, N_EDGES, 48, sorted);
  edge1b_k<<<313,256,0,stream>>>(x1,sh,ww1,esrc,sorted,rowptr,nnb,xM1);
  lin2b_k<<<313,256,0,stream>>>(xM1,w_lin2);

  // edge conv 2: chunked weight-GEMM + row-parallel gather
  if (use_chunk){
    hipMemsetAsync(xM2, 0, 1440000*sizeof(float), stream);
    int nch = (N_EDGES + CHUNK - 1)/CHUNK;
    for (int ci=0; ci<nch; ++ci){
      int rb = ci*CHUNK;
      int re = rb+CHUNK; if (re>N_EDGES) re=N_EDGES;
      int Cc = re-rb;
      gemm16_k<<<dim3((Cc+63)/64,15),256,0,stream>>>(h2, w_fc2+528, ww2, Cc, 960, sorted+rb);
      int waves=(Cc+RPW-1)/RPW;
      int blocks=(waves+3)/4;
      edge2r_k<<<blocks,256,0,stream>>>(xM1, sh, ww2, esrc, sorted, rowptr,
          nnb, cg, xM2, rb, re);
    }
  } else {
    edge2c_k<<<2500,256,0,stream>>>(xM1, sh, h2, w_fc2+528,
        esrc, sorted, rowptr, nnb, cg, xM2);
  }
  lin3b_k<<<313,256,0,stream>>>(xM2,w_lin3);
  node_out_k<<<314,256,0,stream>>>(xM2,w_linC,w_linH,w_s1,w_s2,d_out,flag);

  // bonds (one wave per bond, direct store)
  bond_tpl_k<<<750,256,0,stream>>>(xM2, hb, w_fcb+528,
      esrc, edst, iHH, iCC, iCH, cg, F0, F1, F2);

  // outputs: 0:nH@0 1:nC@250000 2:eHH@2210000 3:eCH@2235000 4:eCC@2305000
  //          5:screen@2501000 6:gapCC@2561000 7:gapHH@2564000 8:gapCH@2567000
  bond_out3_k<<<96,256,0,stream>>>(F0,F1,F2,w_linHH,w_linCC,w_linCH,
      w_g1,w_g2,d_out,flag);
}

// Round 11
// 837.901 us; speedup vs baseline: 1.1149x; 1.1149x over previous
//
#include <hip/hip_runtime.h>
#include <hip/hip_bf16.h>

typedef __hip_bfloat16 bf16_t;

#define N_NODES 10000
#define N_EDGES 100000
#define N_BONDS 1000
#define RPW 4

__device__ __forceinline__ float bf2f(bf16_t v){ return __bfloat162float(v); }
__device__ __forceinline__ bf16_t f2bf(float v){ return __float2bfloat16(v); }
__device__ __forceinline__ int iabs(int x){ return x<0?-x:x; }

// Compile-time CG nonzero superset mask
constexpr bool cg_nz(int l1,int l2,int l3,int i,int j,int k){
  int m1=i-l1, m2=j-l2, m3=k-l3;
  int neg=(m1<0)+(m2<0)+(m3<0);
  if (((neg ^ (l1+l2+l3)) & 1)!=0) return false;
  int a1=m1<0?-m1:m1, a2=m2<0?-m2:m2, a3=m3<0?-m3:m3;
  return (a3==a1+a2)||(a3==a1-a2)||(a3==a2-a1);
}

__device__ __forceinline__ void stout(void* out, size_t idx, float v, bool f32o){
  if (f32o) ((float*)out)[idx]=v;
  else      ((bf16_t*)out)[idx]=f2bf(v);
}

struct CvtArgs {
  const void* src[19];
  float* dst[19];
  int n[19];
};

// =====================================================================
// Convert with inline dtype detection (nnb==10.0; bf16 -> u16[0]==0x4120)
// =====================================================================
__global__ __launch_bounds__(256) void convert_k(CvtArgs a,
    const unsigned short* __restrict__ nnb_raw, int* flag){
  bool f32 = (nnb_raw[0]!=0x4120);
  if (blockIdx.x==0 && threadIdx.x==0) *flag = f32?1:0;
  int tid = blockIdx.x*256+threadIdx.x;
  int nth = gridDim.x*256;
  for(int t=0;t<19;++t){
    int n=a.n[t];
    float* d=a.dst[t];
    if (f32){
      const float* s=(const float*)a.src[t];
      for(int i=tid;i<n;i+=nth) d[i]=s[i];
    } else {
      const bf16_t* s=(const bf16_t*)a.src[t];
      for(int i=tid;i<n;i+=nth) d[i]=bf2f(s[i]);
    }
  }
}

// =====================================================================
// CSR build
// =====================================================================
__global__ __launch_bounds__(256) void csr_count_k(const int* __restrict__ edst, int* __restrict__ cnt){
  int e=blockIdx.x*256+threadIdx.x; if(e>=N_EDGES) return;
  atomicAdd(&cnt[edst[e]],1);
}

__global__ __launch_bounds__(256) void csr_scan_k(const int* __restrict__ cnt,
    int* __restrict__ rowptr, int* __restrict__ pos){
  __shared__ int ssum[256];
  int t=threadIdx.x;
  int base=t*40;
  int s=0;
  for(int i=0;i<40;++i){ int idx=base+i; s += (idx<N_NODES)? cnt[idx]:0; }
  ssum[t]=s; __syncthreads();
  if(t==0){ int run=0; for(int i=0;i<256;++i){ int v=ssum[i]; ssum[i]=run; run+=v; } }
  __syncthreads();
  int run=ssum[t];
  for(int i=0;i<40;++i){
    int idx=base+i;
    if(idx<N_NODES){ rowptr[idx]=run; pos[idx]=run; run+=cnt[idx]; }
  }
  if(t==255) rowptr[N_NODES]=run;
}

__global__ __launch_bounds__(256) void csr_scatter_k(const int* __restrict__ edst,
    int* __restrict__ pos, int* __restrict__ sorted){
  int e=blockIdx.x*256+threadIdx.x; if(e>=N_EDGES) return;
  int p=atomicAdd(&pos[edst[e]],1);
  sorted[p]=e;
}

// =====================================================================
// CG tables
// =====================================================================
__device__ __forceinline__ double dfact(int n){
  const double F[11]={1.,1.,2.,6.,24.,120.,720.,5040.,40320.,362880.,3628800.};
  return F[n];
}

__device__ double cgc_d(int j1,int m1,int j2,int m2,int j3,int m3){
  if (m1+m2!=m3) return 0.0;
  double pre = sqrt((double)(2*j3+1)*dfact(j3+j1-j2)*dfact(j3-j1+j2)*dfact(j1+j2-j3)/dfact(j1+j2+j3+1));
  pre *= sqrt(dfact(j3+m3)*dfact(j3-m3)*dfact(j1-m1)*dfact(j1+m1)*dfact(j2-m2)*dfact(j2+m2));
  int k0 = max(0, max(j2-j3-m1, j1-j3+m2));
  int k1 = min(j1+j2-j3, min(j1-m1, j2+m2));
  double s=0.0;
  for(int k=k0;k<=k1;++k)
    s += ((k&1)?-1.0:1.0)/(dfact(k)*dfact(j1+j2-j3-k)*dfact(j1-m1-k)*dfact(j2+m2-k)*dfact(j3-j2+m1+k)*dfact(j3-j1-m2+k));
  return pre*s;
}

__device__ void c2r_d(int l,int a,int m,double&re,double&im){
  re=0.0; im=0.0;
  const double r2 = 0.7071067811865475244;
  int mu = a-l;
  if (mu==0){ if (m==l) re=1.0; return; }
  if (mu>0){
    if (m==l+mu) re = (mu&1)? -r2 : r2;
    else if (m==l-mu) re = r2;
  } else {
    int nu=-mu;
    if (m==l-nu) im = r2;
    else if (m==l+nu) im = (nu&1)? r2 : -r2;
  }
}

__global__ __launch_bounds__(128) void cg_init_k(float* cg){
  int b=blockIdx.x;
  int l1=b/9, l2=(b/3)%3, l3=b%3;
  if (l3 < iabs(l1-l2) || l3 > l1+l2) return;
  int n1=2*l1+1,n2=2*l2+1,n3=2*l3+1,n=n1*n2*n3;
  __shared__ double sRe[125], sIm[125];
  __shared__ int sPick;
  int t=threadIdx.x;
  if (t<n){
    int a=t/(n2*n3), bb=(t/n3)%n2, c=t%n3;
    double re=0.0, im=0.0;
    for(int m1=0;m1<n1;++m1){
      double q1r,q1i; c2r_d(l1,a,m1,q1r,q1i);
      if (q1r==0.0 && q1i==0.0) continue;
      for(int m2=0;m2<n2;++m2){
        double q2r,q2i; c2r_d(l2,bb,m2,q2r,q2i);
        if (q2r==0.0 && q2i==0.0) continue;
        int m3=(m1-l1)+(m2-l2)+l3;
        if (m3<0||m3>=n3) continue;
        double q3r,q3i; c2r_d(l3,c,m3,q3r,q3i); q3i=-q3i;
        double C = cgc_d(l1,m1-l1,l2,m2-l2,l3,m3-l3);
        if (C==0.0) continue;
        double ar = q1r*q2r - q1i*q2i;
        double ai = q1r*q2i + q1i*q2r;
        re += (ar*q3r - ai*q3i)*C;
        im += (ar*q3i + ai*q3r)*C;
      }
    }
    sRe[t]=re; sIm[t]=im;
  }
  __syncthreads();
  if (t==0){
    double s1=0.0,s2=0.0;
    for(int i=0;i<n;++i){ s1+=fabs(sRe[i]); s2+=fabs(sIm[i]); }
    sPick = (s1>=s2)?1:0;
  }
  __syncthreads();
  if (t<n) cg[b*125+t] = (float)(sPick? sRe[t] : sIm[t]);
}

// =====================================================================
// Stage A
// =====================================================================
__global__ __launch_bounds__(256) void nodeA_k(const float* __restrict__ fin,
                                               const float* __restrict__ w,
                                               float* __restrict__ x1){
  int n=blockIdx.x*256+threadIdx.x; if(n>=N_NODES) return;
  float f0=fin[2*n], f1=fin[2*n+1];
  const float r2=0.70710678f;
  x1[2*n]   = tanhf((f0*w[0]+f1*w[2])*r2);
  x1[2*n+1] = tanhf((f0*w[1]+f1*w[3])*r2);
}

// MLP [1,16,16,16]
__device__ __forceinline__ void mlp16(float e, const float* w, float* h){
  float a[16];
  #pragma unroll
  for(int j=0;j<16;++j) a[j]=fmaxf(e*w[j],0.f);
  float b[16];
  #pragma unroll
  for(int j=0;j<16;++j){
    float s=0.f;
    #pragma unroll
    for(int i=0;i<16;++i) s+=a[i]*w[16+i*16+j];
    b[j]=fmaxf(s*0.25f,0.f);
  }
  #pragma unroll
  for(int j=0;j<16;++j){
    float s=0.f;
    #pragma unroll
    for(int i=0;i<16;++i) s+=b[i]*w[272+i*16+j];
    h[j]=fmaxf(s*0.25f,0.f);
  }
}

// =====================================================================
// Fused h-MLPs: blocks [0,391) -> h1, [391,782) -> h2, [782,794) -> hb
// =====================================================================
__global__ __launch_bounds__(256) void mlps_k(const float* __restrict__ emb,
    const float* __restrict__ wfc1, const float* __restrict__ wfc2,
    const float* __restrict__ wfcb,
    const int* __restrict__ i0, const int* __restrict__ i1,
    const int* __restrict__ i2,
    float* __restrict__ H1, float* __restrict__ H2, float* __restrict__ HB){
  __shared__ float sw[528];
  int b=blockIdx.x;
  const float* wfc; float* H; int eidx; bool ok;
  if (b<391){
    wfc=wfc1; H=H1;
    int e=b*256+threadIdx.x; ok=(e<N_EDGES); eidx= ok? e:0;
  } else if (b<782){
    wfc=wfc2; H=H2;
    int e=(b-391)*256+threadIdx.x; ok=(e<N_EDGES); eidx= ok? e:0;
  } else {
    wfc=wfcb; H=HB;
    int t=(b-782)*256+threadIdx.x; ok=(t<3*N_BONDS);
    eidx=0;
    if (ok){
      const int* ind = (t<N_BONDS)? i0 : (t<2*N_BONDS? i1 : i2);
      eidx = ind[t%N_BONDS];
    }
  }
  for(int t=threadIdx.x;t<528;t+=256) sw[t]=wfc[t];
  __syncthreads();
  if (!ok) return;
  int orow = (b<782)? eidx : ((b-782)*256+threadIdx.x);
  float h[16]; mlp16(emb[eidx], sw, h);
  float4* H4=(float4*)(H+(size_t)orow*16);
  #pragma unroll
  for(int q=0;q<4;++q) H4[q]=make_float4(h[4*q],h[4*q+1],h[4*q+2],h[4*q+3]);
}

// =====================================================================
// C[e x N] = 0.25 * A[idx(e) x 16] * B[16 x N]
// =====================================================================
__global__ __launch_bounds__(256) void gemm16_k(const float* __restrict__ A,
    const float* __restrict__ B, float* __restrict__ C, int Eloc, int N,
    const int* __restrict__ idx){
  __shared__ float As[64][16];
  int tid=threadIdx.x;
  int et=blockIdx.x, ct=blockIdx.y;
  for(int t=tid;t<64*16;t+=256){
    int r=t/16, i=t%16;
    int e=et*64+r;
    int ea=(e<Eloc)? (idx? idx[e]:e) : -1;
    As[r][i]=(ea>=0)? A[(size_t)ea*16+i] : 0.f;
  }
  __syncthreads();
  int col=ct*64+(tid&63);
  int eq=tid>>6;
  bool colok = col<N;
  float Breg[16];
  #pragma unroll
  for(int i=0;i<16;++i) Breg[i]= colok? B[(size_t)i*N+col]*0.25f : 0.f;
  #pragma unroll 4
  for(int es=0;es<16;++es){
    int e=et*64+eq*16+es;
    if (e>=Eloc) break;
    float acc=0.f;
    #pragma unroll
    for(int i=0;i<16;++i) acc+=As[eq*16+es][i]*Breg[i];
    if (colok) C[(size_t)e*N+col]=acc;
  }
}

// =====================================================================
// Edge conv 1: 8 lanes per node, 32 nodes/block.
// =====================================================================
__global__ __launch_bounds__(256) void edge1b_k(const float* __restrict__ x1,
    const float* __restrict__ sh, const float* __restrict__ ww1,
    const int* __restrict__ esrc, const int* __restrict__ sorted,
    const int* __restrict__ rowptr, const float* __restrict__ nnb,
    float* __restrict__ xout){
  int tid=threadIdx.x;
  int n=blockIdx.x*32 + (tid>>3);
  int w8=tid&7;
  if (n>=N_NODES) return;
  float inv = rsqrtf(nnb[0]);
  const float c = 0.70710678f*inv;
  float acc[9];
  #pragma unroll
  for(int t=0;t<9;++t) acc[t]=0.f;
  int r0=rowptr[n], r1=rowptr[n+1];
  for(int r=r0;r<r1;++r){
    int e=sorted[r];
    int src=esrc[e];
    float a0=x1[2*src], a1=x1[2*src+1];
    const float* wr=ww1+(size_t)r*48;
    float w0=wr[w8],    w1=wr[8+w8];
    float w2=wr[16+w8], w3=wr[24+w8];
    float w4=wr[32+w8], w5=wr[40+w8];
    const float* b=sh+(size_t)e*9;
    float s0=w0*a0+w1*a1;
    acc[0]+=s0*b[0];
    float s1=w2*a0+w3*a1;
    #pragma unroll
    for(int j=0;j<3;++j) acc[1+j]+=s1*b[1+j];
    float s2=w4*a0+w5*a1;
    #pragma unroll
    for(int j=0;j<5;++j) acc[4+j]+=s2*b[4+j];
  }
  float* o=xout+(size_t)n*72;
  o[w8]=acc[0]*c;
  #pragma unroll
  for(int j=0;j<3;++j) o[8+w8*3+j]=acc[1+j]*c;
  #pragma unroll
  for(int j=0;j<5;++j) o[32+w8*5+j]=acc[4+j]*c;
}

// =====================================================================
// Block-diagonal linears, LDS-staged
// =====================================================================
__global__ __launch_bounds__(256) void lin2b_k(float* __restrict__ x, const float* __restrict__ w){
  __shared__ float sX[32*72];
  __shared__ float sW[192];
  int tid=threadIdx.x;
  int base=blockIdx.x*32;
  if (tid<192) sW[tid]=w[tid];
  for(int t=tid;t<32*72;t+=256){
    int n=base+t/72;
    sX[t] = (n<N_NODES)? x[(size_t)n*72 + t%72] : 0.f;
  }
  __syncthreads();
  int ns=tid>>3, v=tid&7;
  const float r8=0.35355339f;
  const float* X=sX+ns*72;
  float r[9];
  {
    float a=0.f;
    #pragma unroll
    for(int u=0;u<8;++u) a+=X[u]*sW[u*8+v];
    r[0]=tanhf(a*r8);
  }
  #pragma unroll
  for(int i=0;i<3;++i){
    float a=0.f;
    #pragma unroll
    for(int u=0;u<8;++u) a+=X[8+u*3+i]*sW[64+u*8+v];
    r[1+i]=a*r8;
  }
  #pragma unroll
  for(int i=0;i<5;++i){
    float a=0.f;
    #pragma unroll
    for(int u=0;u<8;++u) a+=X[32+u*5+i]*sW[128+u*8+v];
    r[4+i]=a*r8;
  }
  __syncthreads();
  float* Xw=sX+ns*72;
  Xw[v]=r[0];
  #pragma unroll
  for(int i=0;i<3;++i) Xw[8+v*3+i]=r[1+i];
  #pragma unroll
  for(int i=0;i<5;++i) Xw[32+v*5+i]=r[4+i];
  __syncthreads();
  for(int t=tid;t<32*72;t+=256){
    int n=base+t/72;
    if (n<N_NODES) x[(size_t)n*72 + t%72]=sX[t];
  }
}

__global__ __launch_bounds__(256) void lin3b_k(float* __restrict__ x, const float* __restrict__ w){
  __shared__ float sX[32*144];
  __shared__ float sW[384];
  int tid=threadIdx.x;
  int base=blockIdx.x*32;
  for(int t=tid;t<384;t+=256) sW[t]=w[t];
  for(int t=tid;t<32*144;t+=256){
    int n=base+t/144;
    sX[t] = (n<N_NODES)? x[(size_t)n*144 + t%144] : 0.f;
  }
  __syncthreads();
  int ns=tid>>3, v=tid&7;
  const float r8=0.35355339f;
  const float* X=sX+ns*144;
  float r[18];
  {
    float a=0.f;
    #pragma unroll
    for(int u=0;u<8;++u) a+=X[u]*sW[u*8+v];
    r[0]=tanhf(a*r8);
  }
  {
    float a=0.f;
    #pragma unroll
    for(int u=0;u<8;++u) a+=X[8+u]*sW[64+u*8+v];
    r[1]=tanhf(a*r8);
  }
  #pragma unroll
  for(int i=0;i<3;++i){
    float a=0.f;
    #pragma unroll
    for(int u=0;u<8;++u) a+=X[16+u*3+i]*sW[128+u*8+v];
    r[2+i]=a*r8;
  }
  #pragma unroll
  for(int i=0;i<3;++i){
    float a=0.f;
    #pragma unroll
    for(int u=0;u<8;++u) a+=X[40+u*3+i]*sW[192+u*8+v];
    r[5+i]=a*r8;
  }
  #pragma unroll
  for(int i=0;i<5;++i){
    float a=0.f;
    #pragma unroll
    for(int u=0;u<8;++u) a+=X[64+u*5+i]*sW[256+u*8+v];
    r[8+i]=a*r8;
  }
  #pragma unroll
  for(int i=0;i<5;++i){
    float a=0.f;
    #pragma unroll
    for(int u=0;u<8;++u) a+=X[104+u*5+i]*sW[320+u*8+v];
    r[13+i]=a*r8;
  }
  __syncthreads();
  float* Xw=sX+ns*144;
  Xw[v]=r[0];
  Xw[8+v]=r[1];
  #pragma unroll
  for(int i=0;i<3;++i) Xw[16+v*3+i]=r[2+i];
  #pragma unroll
  for(int i=0;i<3;++i) Xw[40+v*3+i]=r[5+i];
  #pragma unroll
  for(int i=0;i<5;++i) Xw[64+v*5+i]=r[8+i];
  #pragma unroll
  for(int i=0;i<5;++i) Xw[104+v*5+i]=r[13+i];
  __syncthreads();
  for(int t=tid;t<32*144;t+=256){
    int n=base+t/144;
    if (n<N_NODES) x[(size_t)n*144 + t%144]=sX[t];
  }
}

// =====================================================================
// TP path accumulate — compile-time sparsity via cg_nz
// =====================================================================
template<int L1,int L2,int LO,int BO,int SLOT>
__device__ __forceinline__ void tp_acc(const float* Au, const float* b,
    const float* __restrict__ cg, float wv, float* acc){
  constexpr int D1=2*L1+1, D2=2*L2+1, DN=2*LO+1;
  const float* C = cg + ((L1*3+L2)*3+LO)*125;
  float P[DN];
  #pragma unroll
  for(int k=0;k<DN;++k) P[k]=0.f;
  #pragma unroll
  for(int i=0;i<D1;++i){
    float av=Au[i];
    #pragma unroll
    for(int j=0;j<D2;++j){
      #pragma unroll
      for(int k=0;k<DN;++k){
        if (cg_nz(L1,L2,LO,i,j,k)){
          float cv=C[(i*D2+j)*DN+k];
          P[k]+=av*(cv*b[BO+j]);
        }
      }
    }
  }
  #pragma unroll
  for(int k=0;k<DN;++k) acc[SLOT+k]+=wv*P[k];
}

// full-node finish: direct write (fallback kernel only)
__device__ __forceinline__ void e2_finish2(float* acc, float inv, float* __restrict__ o, bool first){
  int lane=threadIdx.x&63;
  int w=lane&7;
  #pragma unroll
  for(int t=0;t<18;++t){
    acc[t]+=__shfl_xor(acc[t],8,64);
    acc[t]+=__shfl_xor(acc[t],16,64);
    acc[t]+=__shfl_xor(acc[t],32,64);
  }
  if (lane<8){
    float f0 =rsqrtf(24.f)*inv;
    float f1e=rsqrtf(16.f)*inv;
    float f1o=rsqrtf(32.f)*inv;
    float f2e=rsqrtf(32.f)*inv;
    float f2o=rsqrtf(16.f)*inv;
    if (first){
      o[0+w]=acc[0]*f0;
      o[8+w]=0.f;
      #pragma unroll
      for(int k=0;k<3;++k) o[16+w*3+k]=acc[2+k]*f1e;
      #pragma unroll
      for(int k=0;k<3;++k) o[40+w*3+k]=acc[5+k]*f1o;
      #pragma unroll
      for(int k=0;k<5;++k) o[64+w*5+k]=acc[8+k]*f2e;
      #pragma unroll
      for(int k=0;k<5;++k) o[104+w*5+k]=acc[13+k]*f2o;
    } else {
      o[0+w]+=acc[0]*f0;
      #pragma unroll
      for(int k=0;k<3;++k) o[16+w*3+k]+=acc[2+k]*f1e;
      #pragma unroll
      for(int k=0;k<3;++k) o[40+w*3+k]+=acc[5+k]*f1o;
      #pragma unroll
      for(int k=0;k<5;++k) o[64+w*5+k]+=acc[8+k]*f2e;
      #pragma unroll
      for(int k=0;k<5;++k) o[104+w*5+k]+=acc[13+k]*f2o;
    }
  }
}

// partial-node flush: atomic accumulate (row-parallel kernel)
__device__ __forceinline__ void e2_flush(float* acc, float inv, float* __restrict__ o){
  int lane=threadIdx.x&63;
  int w=lane&7;
  #pragma unroll
  for(int t=0;t<18;++t){
    acc[t]+=__shfl_xor(acc[t],8,64);
    acc[t]+=__shfl_xor(acc[t],16,64);
    acc[t]+=__shfl_xor(acc[t],32,64);
  }
  if (lane<8){
    float f0 =rsqrtf(24.f)*inv;
    float f1e=rsqrtf(16.f)*inv;
    float f1o=rsqrtf(32.f)*inv;
    float f2e=rsqrtf(32.f)*inv;
    float f2o=rsqrtf(16.f)*inv;
    atomicAdd(&o[0+w], acc[0]*f0);
    #pragma unroll
    for(int k=0;k<3;++k) atomicAdd(&o[16+w*3+k], acc[2+k]*f1e);
    #pragma unroll
    for(int k=0;k<3;++k) atomicAdd(&o[40+w*3+k], acc[5+k]*f1o);
    #pragma unroll
    for(int k=0;k<5;++k) atomicAdd(&o[64+w*5+k], acc[8+k]*f2e);
    #pragma unroll
    for(int k=0;k<5;++k) atomicAdd(&o[104+w*5+k], acc[13+k]*f2o);
  }
}

// shared TP-consume (weights from any address space, offsets in floats)
__device__ __forceinline__ void e2c_consume(const float* __restrict__ xn,
    const float* __restrict__ sh, const float* __restrict__ cg,
    const float* wwp, int e, int src, int u, int lane, float* acc){
  float sv[15];
  sv[ 0]=wwp[  0+lane]; sv[ 1]=wwp[256+lane]; sv[ 2]=wwp[768+lane];
  sv[ 3]=wwp[320+lane]; sv[ 4]=wwp[832+lane];
  sv[ 5]=wwp[ 64+lane]; sv[ 6]=wwp[192+lane]; sv[ 7]=wwp[448+lane]; sv[ 8]=wwp[640+lane];
  sv[ 9]=wwp[128+lane]; sv[10]=wwp[384+lane]; sv[11]=wwp[576+lane]; sv[12]=wwp[896+lane];
  sv[13]=wwp[512+lane]; sv[14]=wwp[704+lane];
  const float* A = xn + (size_t)src*72;
  float b[9];
  #pragma unroll
  for(int j=0;j<9;++j) b[j]=sh[(size_t)e*9+j];
  float a0[1]; a0[0]=A[u];
  float a1[3];
  #pragma unroll
  for(int i=0;i<3;++i) a1[i]=A[8+u*3+i];
  float a2[5];
  #pragma unroll
  for(int i=0;i<5;++i) a2[i]=A[32+u*5+i];
  tp_acc<0,0,0,0, 0>(a0,b,cg,sv[ 0],acc);
  tp_acc<1,1,0,1, 0>(a1,b,cg,sv[ 1],acc);
  tp_acc<2,2,0,4, 0>(a2,b,cg,sv[ 2],acc);
  tp_acc<1,1,1,1, 2>(a1,b,cg,sv[ 3],acc);
  tp_acc<2,2,1,4, 2>(a2,b,cg,sv[ 4],acc);
  tp_acc<0,1,1,1, 5>(a0,b,cg,sv[ 5],acc);
  tp_acc<1,0,1,0, 5>(a1,b,cg,sv[ 6],acc);
  tp_acc<1,2,1,4, 5>(a1,b,cg,sv[ 7],acc);
  tp_acc<2,1,1,1, 5>(a2,b,cg,sv[ 8],acc);
  tp_acc<0,2,2,4, 8>(a0,b,cg,sv[ 9],acc);
  tp_acc<1,1,2,1, 8>(a1,b,cg,sv[10],acc);
  tp_acc<2,0,2,0, 8>(a2,b,cg,sv[11],acc);
  tp_acc<2,2,2,4, 8>(a2,b,cg,sv[12],acc);
  tp_acc<1,2,2,4,13>(a1,b,cg,sv[13],acc);
  tp_acc<2,1,2,1,13>(a2,b,cg,sv[14],acc);
}

// =====================================================================
// Edge conv 2 PRIMARY (row-parallel): wave handles RPW CSR rows of the
// chunk [rb,re); binary-search start node; per-node register acc; on
// node boundary flush via atomicAdd into pre-zeroed xout.
// =====================================================================
__global__ __launch_bounds__(256) void edge2r_k(const float* __restrict__ xn,
    const float* __restrict__ sh, const float* __restrict__ ww2,
    const int* __restrict__ esrc, const int* __restrict__ sorted,
    const int* __restrict__ rowptr, const float* __restrict__ nnb,
    const float* __restrict__ cg, float* __restrict__ xout,
    int rb, int re){
  int gw=blockIdx.x*4+(threadIdx.x>>6);
  int lane=threadIdx.x&63;
  int u=lane>>3;
  int rs=rb+gw*RPW;
  if (rs>=re) return;
  int rend=min(rs+RPW, re);
  float inv=rsqrtf(nnb[0]);
  // largest n with rowptr[n] <= rs  (handles empty nodes correctly)
  int lo=0, hi=N_NODES-1;
  while(lo<hi){ int mid=(lo+hi+1)>>1; if(rowptr[mid]<=rs) lo=mid; else hi=mid-1; }
  int n=lo;
  int nend=rowptr[n+1];
  float acc[18];
  #pragma unroll
  for(int t=0;t<18;++t) acc[t]=0.f;
  bool dirty=false;
  for(int r=rs;r<rend;++r){
    while(r>=nend){
      if (dirty){
        e2_flush(acc, inv, xout+(size_t)n*144);
        #pragma unroll
        for(int t=0;t<18;++t) acc[t]=0.f;
        dirty=false;
      }
      n++; nend=rowptr[n+1];
    }
    int e=__builtin_amdgcn_readfirstlane(sorted[r]);
    int src=__builtin_amdgcn_readfirstlane(esrc[e]);
    e2c_consume(xn,sh,cg, ww2+(size_t)(r-rb)*960, e,src,u,lane,acc);
    dirty=true;
  }
  if (dirty) e2_flush(acc, inv, xout+(size_t)n*144);
}

// =====================================================================
// Edge conv 2 FALLBACK (tiny workspace): cooperative per-edge ww-GEMM
// =====================================================================
__global__ __launch_bounds__(256) void edge2c_k(const float* __restrict__ xn,
    const float* __restrict__ sh, const float* __restrict__ h2,
    const float* __restrict__ Wg, const int* __restrict__ esrc,
    const int* __restrict__ sorted, const int* __restrict__ rowptr,
    const float* __restrict__ nnb, const float* __restrict__ cg,
    float* __restrict__ xout){
  __shared__ float ww[2][4][960];
  __shared__ int sE[4];
  __shared__ int sCnt[4];
  int tid=threadIdx.x, wid=tid>>6, lane=tid&63;
  int n=blockIdx.x*4+wid;
  int u=lane>>3;
  float inv=rsqrtf(nnb[0]);
  int r0=rowptr[n], r1=rowptr[n+1];
  if (lane==0) sCnt[wid]=r1-r0;
  __syncthreads();
  int mx = max(max(sCnt[0],sCnt[1]),max(sCnt[2],sCnt[3]));
  float acc[18];
  #pragma unroll
  for(int t=0;t<18;++t) acc[t]=0.f;
  int pe=0, psrc=0; bool pact=false;
  for(int t=0;t<mx;++t){
    int r=r0+t;
    bool act=(r<r1);
    int e=0, src=0;
    if (act){
      e=__builtin_amdgcn_readfirstlane(sorted[r]);
      src=__builtin_amdgcn_readfirstlane(esrc[e]);
    }
    if (lane==0) sE[wid]= act? e : -1;
    __syncthreads();
    if (tid<240){
      int e0=max(sE[0],0), e1=max(sE[1],0), e2i=max(sE[2],0), e3=max(sE[3],0);
      const float* h0=h2+(size_t)e0*16;
      const float* h1=h2+(size_t)e1*16;
      const float* hq=h2+(size_t)e2i*16;
      const float* h3=h2+(size_t)e3*16;
      float4 av[4];
      #pragma unroll
      for(int k=0;k<4;++k) av[k]=make_float4(0.f,0.f,0.f,0.f);
      #pragma unroll
      for(int i=0;i<16;++i){
        float hx=h0[i], hy=h1[i], hz=hq[i], hw=h3[i];
        const float* Wr=Wg+i*960;
        #pragma unroll
        for(int k=0;k<4;++k){
          float w=Wr[tid+240*k];
          av[k].x+=hx*w; av[k].y+=hy*w; av[k].z+=hz*w; av[k].w+=hw*w;
        }
      }
      float* wb=&ww[t&1][0][0];
      #pragma unroll
      for(int k=0;k<4;++k){
        int c=tid+240*k;
        wb[c]=av[k].x*0.25f; wb[960+c]=av[k].y*0.25f;
        wb[1920+c]=av[k].z*0.25f; wb[2880+c]=av[k].w*0.25f;
      }
    }
    if (pact){
      const float* wwp=&ww[(t&1)^1][wid][0];
      e2c_consume(xn,sh,cg,wwp,pe,psrc,u,lane,acc);
    }
    pe=e; psrc=src; pact=act;
    __syncthreads();
  }
  if (pact){
    const float* wwp=&ww[(mx-1)&1][wid][0];
    e2c_consume(xn,sh,cg,wwp,pe,psrc,u,lane,acc);
  }
  e2_finish2(acc, inv, xout+(size_t)n*144, true);
}

// =====================================================================
// Irrep linear with input-slice range + optional zero-fill
// =====================================================================
struct IrS{ short off,m,l,p; };
__device__ const IrS SL_MID2[6]={{0,8,0,1},{8,8,0,-1},{16,8,1,1},{40,8,1,-1},{64,8,2,1},{104,8,2,-1}};
__device__ const IrS SL_HH[6]={{0,4,0,1},{4,2,1,-1},{10,2,1,-1},{16,1,0,1},{17,1,1,1},{20,1,2,1}};
__device__ const IrS SL_CC[34]={{0,9,0,1},{9,6,1,-1},{27,3,2,1},{42,6,1,-1},
 {60,1,0,1},{61,1,1,1},{64,1,2,1},{69,1,0,1},{70,1,1,1},{73,1,2,1},
 {78,1,0,1},{79,1,1,1},{82,1,2,1},{87,1,0,1},{88,1,1,1},{91,1,2,1},
 {96,1,1,-1},{99,1,2,-1},{104,1,3,-1},{111,1,1,-1},{114,1,2,-1},{119,1,3,-1},
 {126,3,2,1},{141,1,1,-1},{144,1,2,-1},{149,1,3,-1},{156,1,1,-1},{159,1,2,-1},{164,1,3,-1},
 {171,1,0,1},{172,1,1,1},{175,1,2,1},{180,1,3,1},{187,1,4,1}};
__device__ const IrS SL_CH[13]={{0,6,0,1},{6,3,1,-1},{15,4,1,-1},{27,1,0,1},{28,1,1,1},{31,1,2,1},
 {36,1,0,1},{37,1,1,1},{40,1,2,1},{45,2,2,1},{55,1,1,-1},{58,1,2,-1},{63,1,3,-1}};

__device__ void lin_out_r(const float* __restrict__ x, bool act16, const float* __restrict__ w,
                          const IrS* so, int no, void* out, size_t base, bool f32o,
                          float scale, int aBeg, int aEnd, bool zf){
  float tx[16];
  bool need_tx = act16 && (aBeg<2);
  if (need_tx){
    #pragma unroll
    for(int i=0;i<16;++i) tx[i]=tanhf(x[i]);
  }
  if (zf){
    for(int bI=0;bI<no;++bI){
      if (so[bI].l>=3){
        int cnt=so[bI].m*(2*so[bI].l+1);
        for(int t=0;t<cnt;++t) stout(out, base+so[bI].off+t, 0.f, f32o);
      }
    }
  }
  int woff=0;
  float f = 0.35355339f*scale;
  for(int a=0;a<6;++a){
    int la=SL_MID2[a].l, pa=SL_MID2[a].p, oa=SL_MID2[a].off;
    int d=2*la+1;
    bool doit = (a>=aBeg && a<aEnd);
    for(int bI=0;bI<no;++bI){
      if (so[bI].l!=la || so[bI].p!=pa) continue;
      int mo=so[bI].m;
      if (doit){
        for(int v=0;v<mo;++v){
          for(int i=0;i<d;++i){
            float acc=0.f;
            for(int u=0;u<8;++u){
              int idx=oa+u*d+i;
              float xv=(act16 && idx<16)? tx[idx] : x[idx];
              acc+=xv*w[woff+u*mo+v];
            }
            stout(out, base+so[bI].off+v*d+i, acc*f, f32o);
          }
        }
      }
      woff+=8*mo;
    }
  }
}

// =====================================================================
// Node outputs: WAVE-level job split.
// =====================================================================
__global__ __launch_bounds__(256) void node_out_k(const float* __restrict__ x,
    const float* __restrict__ wC, const float* __restrict__ wH,
    const float* __restrict__ ws1, const float* __restrict__ ws2,
    void* out, const int* __restrict__ flag){
  int tid=threadIdx.x;
  int gw=blockIdx.x*4+(tid>>6);
  int lane=tid&63;
  int job=gw&7;
  int n=(gw>>3)*64+lane;
  if (n>=N_NODES) return;
  bool f32o = (*flag)!=0;
  const float* X = x + (size_t)n*144;
  if (job==0){
    lin_out_r(X,false,wH,SL_HH,6, out, (size_t)n*25, f32o, 0.2f, 0,6, true);
  } else if (job==1){
    const float r8=0.35355339f, r32=0.17677670f;
    float t0[32];
    for(int v=0;v<32;++v){
      float acc=0.f;
      #pragma unroll
      for(int u=0;u<8;++u) acc+=X[u]*ws1[u*32+v];
      t0[v]=tanhf(acc*r8);
    }
    float t2[5];
    #pragma unroll
    for(int i=0;i<5;++i){
      float acc=0.f;
      #pragma unroll
      for(int u=0;u<8;++u) acc+=X[64+u*5+i]*ws1[256+u];
      t2[i]=acc*r8;
    }
    size_t sb = 2501000 + (size_t)n*6;
    float acc=0.f;
    for(int v=0;v<32;++v) acc+=t0[v]*ws2[v];
    stout(out, sb, acc*r32, f32o);
    float w2e=ws2[32];
    #pragma unroll
    for(int i=0;i<5;++i) stout(out, sb+1+i, t2[i]*w2e, f32o);
  } else {
    int a=job-2;
    lin_out_r(X,false,wC,SL_CC,34, out, 250000 + (size_t)n*196, f32o, 0.2f,
              a, a+1, a==0);
  }
}

// =====================================================================
// Bond TP (scalar form, measured best): one wave per bond, 60 paths,
// cooperative ww-GEMM double-buffered, direct store.
// =====================================================================
template<int L1,int L2,int LO>
__device__ __forceinline__ void bond_path2(const float* sa,int ao,const float* sb,int bo,
    const float* __restrict__ cg, const float* __restrict__ wwp,
    float invfan, float* sF, int oo, int lane){
  constexpr int D1=2*L1+1, D2=2*L2+1, DN=2*LO+1;
  const float* C = cg + ((L1*3+L2)*3+LO)*125;
  int u=lane>>3, v=lane&7;
  float P[DN];
  #pragma unroll
  for(int k=0;k<DN;++k) P[k]=0.f;
  #pragma unroll
  for(int i=0;i<D1;++i){
    float avv=sa[ao+u*D1+i];
    #pragma unroll
    for(int j=0;j<D2;++j){
      #pragma unroll
      for(int k=0;k<DN;++k){
        if (cg_nz(L1,L2,LO,i,j,k)){
          float cv=C[(i*D2+j)*DN+k];
          P[k]+=(avv*sb[bo+v*D2+j])*cv;
        }
      }
    }
  }
  int v2=u;
  float acc[DN];
  #pragma unroll
  for(int k=0;k<DN;++k) acc[k]=0.f;
  #pragma unroll
  for(int u2=0;u2<8;++u2){
    float ww=wwp[u2*64 + lane];
    int srcl=u2*8+v2;
    #pragma unroll
    for(int k=0;k<DN;++k) acc[k]+=ww*__shfl(P[k],srcl,64);
  }
  #pragma unroll
  for(int k=0;k<DN;++k){
    acc[k]+=__shfl_xor(acc[k],8,64);
    acc[k]+=__shfl_xor(acc[k],16,64);
    acc[k]+=__shfl_xor(acc[k],32,64);
  }
  int w=lane&7;
  if (v2==0){
    #pragma unroll
    for(int k=0;k<DN;++k) sF[oo+w*DN+k]+=acc[k]*invfan;
  }
}

__device__ __forceinline__ void bond_disp(int code, const float* a,int ao,const float* bb,int bo,
    const float* __restrict__ cg, const float* __restrict__ wwp,
    float fv, float* Ff, int oo, int lane){
  switch(code){
    case 0:  bond_path2<0,0,0>(a,ao,bb,bo,cg,wwp,fv,Ff,oo,lane); break;
    case 4:  bond_path2<0,1,1>(a,ao,bb,bo,cg,wwp,fv,Ff,oo,lane); break;
    case 8:  bond_path2<0,2,2>(a,ao,bb,bo,cg,wwp,fv,Ff,oo,lane); break;
    case 10: bond_path2<1,0,1>(a,ao,bb,bo,cg,wwp,fv,Ff,oo,lane); break;
    case 12: bond_path2<1,1,0>(a,ao,bb,bo,cg,wwp,fv,Ff,oo,lane); break;
    case 13: bond_path2<1,1,1>(a,ao,bb,bo,cg,wwp,fv,Ff,oo,lane); break;
    case 14: bond_path2<1,1,2>(a,ao,bb,bo,cg,wwp,fv,Ff,oo,lane); break;
    case 16: bond_path2<1,2,1>(a,ao,bb,bo,cg,wwp,fv,Ff,oo,lane); break;
    case 17: bond_path2<1,2,2>(a,ao,bb,bo,cg,wwp,fv,Ff,oo,lane); break;
    case 20: bond_path2<2,0,2>(a,ao,bb,bo,cg,wwp,fv,Ff,oo,lane); break;
    case 22: bond_path2<2,1,1>(a,ao,bb,bo,cg,wwp,fv,Ff,oo,lane); break;
    case 23: bond_path2<2,1,2>(a,ao,bb,bo,cg,wwp,fv,Ff,oo,lane); break;
    case 24: bond_path2<2,2,0>(a,ao,bb,bo,cg,wwp,fv,Ff,oo,lane); break;
    case 25: bond_path2<2,2,1>(a,ao,bb,bo,cg,wwp,fv,Ff,oo,lane); break;
    case 26: bond_path2<2,2,2>(a,ao,bb,bo,cg,wwp,fv,Ff,oo,lane); break;
  }
}

__global__ __launch_bounds__(256) void bond_tpl_k(const float* __restrict__ xn,
    const float* __restrict__ hb, const float* __restrict__ Wg,
    const int* __restrict__ esrc, const int* __restrict__ edst,
    const int* __restrict__ i0, const int* __restrict__ i1,
    const int* __restrict__ i2, const float* __restrict__ cg,
    float* __restrict__ F0, float* __restrict__ F1, float* __restrict__ F2){
  __shared__ float sA[4][144], sB[4][144], sF[4][144];
  __shared__ float ww[2][2048];
  int tid=threadIdx.x;
  int wid=tid>>6, lane=tid&63;
  int gb=blockIdx.x*4+wid;
  int s=gb/N_BONDS, bi=gb-s*N_BONDS;
  const int* ind=(s==0)?i0:(s==1)?i1:i2;
  float* F=(s==0)?F0:(s==1)?F1:F2;
  int ie=ind[bi];
  int src=esrc[ie], dst=edst[ie];
  for(int t=lane;t<144;t+=64){
    sA[wid][t]=xn[(size_t)src*144+t];
    sB[wid][t]=xn[(size_t)dst*144+t];
    sF[wid][t]=0.f;
  }
  float4 hreg[16];
  {
    size_t hbase=(size_t)blockIdx.x*64;
    #pragma unroll
    for(int i=0;i<16;++i)
      hreg[i]=make_float4(hb[hbase+i],hb[hbase+16+i],hb[hbase+32+i],hb[hbase+48+i]);
  }
  const int SL_L[6]={0,0,1,1,2,2};
  const int SL_P[6]={1,-1,1,-1,1,-1};
  const int SL_O[6]={0,8,16,40,64,104};
  const float fi0=rsqrtf(384.f), fi1=rsqrtf(768.f);
  int pidx=0;
  int pcode=0, pao=0, pbo=0, poo=0; float pfv=0.f;
  for(int s1=0;s1<6;++s1){
    for(int s2=0;s2<6;++s2){
      for(int so=0;so<6;++so){
        int l1=SL_L[s1], l2=SL_L[s2], lo=SL_L[so];
        if (SL_P[so]!=SL_P[s1]*SL_P[s2]) continue;
        if (lo<iabs(l1-l2) || lo>l1+l2) continue;
        {
          const float* Wp = Wg + (size_t)pidx*512;
          float4 a0=make_float4(0.f,0.f,0.f,0.f);
          float4 a1=make_float4(0.f,0.f,0.f,0.f);
          #pragma unroll
          for(int i=0;i<16;++i){
            float w0=Wp[(size_t)i*30720 + tid];
            float w1=Wp[(size_t)i*30720 + tid + 256];
            float4 h=hreg[i];
            a0.x+=h.x*w0; a0.y+=h.y*w0; a0.z+=h.z*w0; a0.w+=h.w*w0;
            a1.x+=h.x*w1; a1.y+=h.y*w1; a1.z+=h.z*w1; a1.w+=h.w*w1;
          }
          float* wb=ww[pidx&1];
          wb[0*512+tid]    =a0.x*0.25f;
          wb[1*512+tid]    =a0.y*0.25f;
          wb[2*512+tid]    =a0.z*0.25f;
          wb[3*512+tid]    =a0.w*0.25f;
          wb[0*512+tid+256]=a1.x*0.25f;
          wb[1*512+tid+256]=a1.y*0.25f;
          wb[2*512+tid+256]=a1.z*0.25f;
          wb[3*512+tid+256]=a1.w*0.25f;
        }
        if (pidx>0){
          const float* wwp = ww[(pidx-1)&1] + wid*512;
          bond_disp(pcode, sA[wid], pao, sB[wid], pbo, cg, wwp, pfv, sF[wid], poo, lane);
        }
        pcode=l1*9+l2*3+lo; pao=SL_O[s1]; pbo=SL_O[s2]; poo=SL_O[so];
        pfv=(lo==0)? fi0 : fi1;
        pidx++;
        __syncthreads();
      }
    }
  }
  {
    const float* wwp = ww[(pidx-1)&1] + wid*512;
    bond_disp(pcode, sA[wid], pao, sB[wid], pbo, cg, wwp, pfv, sF[wid], poo, lane);
  }
  __syncthreads();
  for(int t=lane;t<144;t+=64) F[(size_t)bi*144+t]=sF[wid][t];
}

// =====================================================================
// Bond outputs: single fused launch, WAVE-level job split.
// =====================================================================
__global__ __launch_bounds__(256) void bond_out3_k(
    const float* __restrict__ F0, const float* __restrict__ F1,
    const float* __restrict__ F2,
    const float* __restrict__ wHH, const float* __restrict__ wCC,
    const float* __restrict__ wCH,
    const float* __restrict__ wg1, const float* __restrict__ wg2,
    void* out, const int* __restrict__ flag){
  int tbl=blockIdx.x>>5;
  int blk=blockIdx.x&31;
  int tid=threadIdx.x;
  int gw=blk*4+(tid>>6);
  int lane=tid&63;
  int job=gw&7;
  int n=(gw>>3)*64+lane;
  if (n>=N_BONDS) return;
  bool f32o = (*flag)!=0;
  const float* F = (tbl==0)?F0:(tbl==1)?F1:F2;
  const float* wlin = (tbl==0)?wHH:(tbl==1)?wCC:wCH;
  size_t baseE = (tbl==0)?2210000u:(tbl==1)?2305000u:2235000u;
  size_t baseG = (tbl==0)?2564000u:(tbl==1)?2561000u:2567000u;
  const float* X=F+(size_t)n*144;
  if (job==0){
    const float r8=0.35355339f, r32=0.17677670f;
    float g[32];
    for(int v=0;v<32;++v){
      float acc=0.f;
      #pragma unroll
      for(int u=0;u<8;++u) acc+=X[u]*wg1[u*32+v];
      g[v]=tanhf(acc*r8);
    }
    #pragma unroll
    for(int c=0;c<3;++c){
      float acc=0.f;
      for(int v=0;v<32;++v) acc+=g[v]*wg2[v*3+c];
      stout(out, baseG+(size_t)n*3+c, acc*r32, f32o);
    }
  } else if (job>=2){
    const IrS* so; int no; int dim;
    if(tbl==0){so=SL_HH;no=6;dim=25;}
    else if(tbl==1){so=SL_CC;no=34;dim=196;}
    else {so=SL_CH;no=13;dim=70;}
    int a=job-2;
    lin_out_r(X,true,wlin,so,no,out,baseE+(size_t)n*dim,f32o,0.2f,
              a, a+1, a==0);
  }
}

// =====================================================================
extern "C" void kernel_launch(void* const* d_in, const int* in_sizes, int n_in,
                              void* d_out, int out_size, void* d_ws, size_t ws_size,
                              hipStream_t stream){
  const int* esrc=(const int*)d_in[19];
  const int* edst=(const int*)d_in[20];
  const int* iHH =(const int*)d_in[21];
  const int* iCC =(const int*)d_in[22];
  const int* iCH =(const int*)d_in[23];
  float* ws=(float*)d_ws;
  int* flag=(int*)d_ws;

  size_t off=16;
  auto alloc=[&](size_t n){ size_t o=off; off+=(n+15)&~(size_t)15; return o; };
  size_t o_cg = alloc(27*125);
  size_t o_st[19];
  for(int i=0;i<19;++i) o_st[i]=alloc((size_t)in_sizes[i]);
  size_t o_xM1 = alloc(720000);
  size_t o_xM2 = alloc(1440000);
  size_t o_h2  = alloc((size_t)N_EDGES*16);
  size_t o_hb  = alloc((size_t)3*N_BONDS*16);
  size_t o_cnt = alloc(10016);
  size_t o_rp  = alloc(10016);
  size_t o_pos = alloc(10016);
  size_t o_srt = alloc(N_EDGES);
  // TAIL: everything below is dead during edge conv 2 -> reused as ww2
  size_t o_x1  = alloc(20000);
  size_t o_F0  = alloc(144000);
  size_t o_F1  = alloc(144000);
  size_t o_F2  = alloc(144000);
  size_t o_h1  = alloc((size_t)N_EDGES*16);
  size_t o_ww1 = alloc((size_t)N_EDGES*48);
  (void)o_ww1;

  float* cg  = ws+o_cg;
  float* x1  = ws+o_x1;
  float* xM1 = ws+o_xM1;
  float* xM2 = ws+o_xM2;
  float* F0  = ws+o_F0;
  float* F1  = ws+o_F1;
  float* F2  = ws+o_F2;
  float* h1  = ws+o_h1;
  float* h2  = ws+o_h2;
  float* hb  = ws+o_hb;
  float* ww1 = ws+o_ww1;
  int* cnt   = (int*)(ws+o_cnt);
  int* rowptr= (int*)(ws+o_rp);
  int* pos   = (int*)(ws+o_pos);
  int* sorted= (int*)(ws+o_srt);

  // ww2 reuses x1+F+h1+ww1+slack (all dead during edge conv 2)
  size_t totf = ws_size/sizeof(float);
  size_t availf = (totf>o_x1)? totf-o_x1 : 0;
  int CHUNK = (int)((availf/960 < (size_t)N_EDGES)? availf/960 : (size_t)N_EDGES);
  bool use_chunk = (CHUNK >= 2000);
  float* ww2 = ws + o_x1;

  CvtArgs ca;
  for(int i=0;i<19;++i){ ca.src[i]=d_in[i]; ca.dst[i]=ws+o_st[i]; ca.n[i]=in_sizes[i]; }
  const float* f_in   = ws+o_st[0];
  const float* sh     = ws+o_st[1];
  const float* emb    = ws+o_st[2];
  const float* nnb    = ws+o_st[3];
  const float* w_lin1 = ws+o_st[4];
  const float* w_lin2 = ws+o_st[5];
  const float* w_lin3 = ws+o_st[6];
  const float* w_linCC= ws+o_st[7];
  const float* w_linHH= ws+o_st[8];
  const float* w_linCH= ws+o_st[9];
  const float* w_linC = ws+o_st[10];
  const float* w_linH = ws+o_st[11];
  const float* w_s1   = ws+o_st[12];
  const float* w_s2   = ws+o_st[13];
  const float* w_g1   = ws+o_st[14];
  const float* w_g2   = ws+o_st[15];
  const float* w_fc1  = ws+o_st[16];
  const float* w_fc2  = ws+o_st[17];
  const float* w_fcb  = ws+o_st[18];

  convert_k<<<512,256,0,stream>>>(ca, (const unsigned short*)d_in[3], flag);
  cg_init_k<<<27,128,0,stream>>>(cg);
  // CSR by destination
  hipMemsetAsync(cnt, 0, 10000*sizeof(int), stream);
  csr_count_k<<<391,256,0,stream>>>(edst, cnt);
  csr_scan_k<<<1,256,0,stream>>>(cnt, rowptr, pos);
  csr_scatter_k<<<391,256,0,stream>>>(edst, pos, sorted);

  nodeA_k<<<40,256,0,stream>>>(f_in,w_lin1,x1);
  mlps_k<<<794,256,0,stream>>>(emb, w_fc1, w_fc2, w_fcb, iHH, iCC, iCH, h1, h2, hb);

  // edge conv 1
  gemm16_k<<<dim3(1563,1),256,0,stream>>>(h1, w_fc1+528, ww1, N_EDGES, 48, sorted);
  edge1b_k<<<313,256,0,stream>>>(x1,sh,ww1,esrc,sorted,rowptr,nnb,xM1);
  lin2b_k<<<313,256,0,stream>>>(xM1,w_lin2);

  // edge conv 2: chunked weight-GEMM + row-parallel gather
  if (use_chunk){
    hipMemsetAsync(xM2, 0, 1440000*sizeof(float), stream);
    int nch = (N_EDGES + CHUNK - 1)/CHUNK;
    for (int ci=0; ci<nch; ++ci){
      int rb = ci*CHUNK;
      int re = rb+CHUNK; if (re>N_EDGES) re=N_EDGES;
      int Cc = re-rb;
      gemm16_k<<<dim3((Cc+63)/64,15),256,0,stream>>>(h2, w_fc2+528, ww2, Cc, 960, sorted+rb);
      int waves=(Cc+RPW-1)/RPW;
      int blocks=(waves+3)/4;
      edge2r_k<<<blocks,256,0,stream>>>(xM1, sh, ww2, esrc, sorted, rowptr,
          nnb, cg, xM2, rb, re);
    }
  } else {
    edge2c_k<<<2500,256,0,stream>>>(xM1, sh, h2, w_fc2+528,
        esrc, sorted, rowptr, nnb, cg, xM2);
  }
  lin3b_k<<<313,256,0,stream>>>(xM2,w_lin3);
  node_out_k<<<314,256,0,stream>>>(xM2,w_linC,w_linH,w_s1,w_s2,d_out,flag);

  // bonds (one wave per bond, direct store)
  bond_tpl_k<<<750,256,0,stream>>>(xM2, hb, w_fcb+528,
      esrc, edst, iHH, iCC, iCH, cg, F0, F1, F2);

  // outputs: 0:nH@0 1:nC@250000 2:eHH@2210000 3:eCH@2235000 4:eCC@2305000
  //          5:screen@2501000 6:gapCC@2561000 7:gapHH@2564000 8:gapCH@2567000
  bond_out3_k<<<96,256,0,stream>>>(F0,F1,F2,w_linHH,w_linCC,w_linCH,
      w_g1,w_g2,d_out,flag);
}